// Round 6
// baseline (502.480 us; speedup 1.0000x reference)
//
#include <hip/hip_runtime.h>

typedef unsigned short u16;
typedef _Float16 f16x8 __attribute__((ext_vector_type(8)));
typedef float f32x4 __attribute__((ext_vector_type(4)));
typedef u16 u16x4 __attribute__((ext_vector_type(4)));
typedef u16 u16x8v __attribute__((ext_vector_type(8)));

__device__ __forceinline__ u16 f2h(float f) {
    _Float16 h = (_Float16)f;
    return __builtin_bit_cast(u16, h);
}
__device__ __forceinline__ float h2f(u16 u) {
    return (float)__builtin_bit_cast(_Float16, u);
}

// ---------------------------------------------------------------- stats ----
__global__ void __launch_bounds__(256) stats_kernel(
    const float* __restrict__ c, const float* __restrict__ s,
    float* __restrict__ mC, float* __restrict__ rC,
    float* __restrict__ mS, float* __restrict__ rS)
{
    const float* src = (blockIdx.y ? s : c) + (size_t)blockIdx.x * 4096;
    int t = threadIdx.x, lane = t & 63, wv = t >> 6;
    const float4* p = (const float4*)src;
    float sum = 0.f, sq = 0.f;
#pragma unroll
    for (int i = 0; i < 4; ++i) {
        float4 v = p[t + 256 * i];
        sum += v.x + v.y + v.z + v.w;
        sq  += v.x * v.x + v.y * v.y + v.z * v.z + v.w * v.w;
    }
#pragma unroll
    for (int m = 1; m < 64; m <<= 1) {
        sum += __shfl_xor(sum, m);
        sq  += __shfl_xor(sq, m);
    }
    __shared__ float sa[4], sb[4];
    if (!lane) { sa[wv] = sum; sb[wv] = sq; }
    __syncthreads();
    if (t == 0) {
        float S = sa[0] + sa[1] + sa[2] + sa[3];
        float Q = sb[0] + sb[1] + sb[2] + sb[3];
        float mean = S * (1.0f / 4096.0f);
        float var = (Q - 4096.0f * mean * mean) * (1.0f / 4095.0f);
        float rstd = rsqrtf(var + 1e-5f);
        if (blockIdx.y) { mS[blockIdx.x] = mean; rS[blockIdx.x] = rstd; }
        else            { mC[blockIdx.x] = mean; rC[blockIdx.x] = rstd; }
    }
}

// ------------------------------------------------------- transpose pack ----
// MODE 0: dh = transposed normalized [B,N,C] f16.
// MODE 3: dh = transposed normalized; dl = NATURAL raw [B,C,N] f16.
template<int MODE>
__global__ void __launch_bounds__(256) pack_kernel(
    const float* __restrict__ src, const float* __restrict__ mean,
    const float* __restrict__ rstd, u16* __restrict__ dh, u16* __restrict__ dl)
{
    __shared__ float tile[32][33];
    int b = blockIdx.z, n0 = blockIdx.x * 32, c0 = blockIdx.y * 32;
    int tx = threadIdx.x, ty = threadIdx.y;
    const float* sbp = src + ((size_t)b * 512 + c0) * 4096 + n0;
#pragma unroll
    for (int it = 0; it < 4; ++it) {
        int cc = ty + it * 8;
        float v = sbp[(size_t)cc * 4096 + tx];
        tile[cc][tx] = v;
        if (MODE == 3)
            dl[((size_t)b * 512 + c0 + cc) * 4096 + n0 + tx] = f2h(v);
    }
    __syncthreads();
    int ch = c0 + tx;
    float mn = mean[b * 512 + ch];
    float rs = rstd[b * 512 + ch];
    size_t obase = ((size_t)b * 4096 + n0) * 512 + c0;
#pragma unroll
    for (int it = 0; it < 4; ++it) {
        int r = ty + it * 8;
        dh[obase + (size_t)r * 512 + tx] = f2h((tile[tx][r] - mn) * rs);
    }
}

// ------------------------------------------------------------ wt packs ----
__global__ void __launch_bounds__(256) split_f16(
    const float* __restrict__ src, u16* __restrict__ h, int n)
{
    int i = blockIdx.x * 256 + threadIdx.x;
    if (i < n) h[i] = f2h(src[i]);
}

// wT[c][k] = w[k][c], 512x512 fp32 -> f16
__global__ void __launch_bounds__(256) tpack512(
    const float* __restrict__ w, u16* __restrict__ wT)
{
    __shared__ float tile[32][33];
    int c0 = blockIdx.x * 32, k0 = blockIdx.y * 32;
    int tx = threadIdx.x, ty = threadIdx.y;
#pragma unroll
    for (int it = 0; it < 4; ++it) {
        int kk = ty + it * 8;
        tile[kk][tx] = w[(size_t)(k0 + kk) * 512 + c0 + tx];
    }
    __syncthreads();
#pragma unroll
    for (int it = 0; it < 4; ++it) {
        int r = ty + it * 8;
        wT[(size_t)(c0 + r) * 512 + k0 + tx] = f2h(tile[tx][r]);
    }
}

// v[o] = o_b[o] + sum_k o_w[o,k] * i_b[k]   (fp32 inputs)
__global__ void __launch_bounds__(256) vbias_kernel(
    const float* __restrict__ o_w, const float* __restrict__ i_b,
    const float* __restrict__ o_b, float* __restrict__ v)
{
    __shared__ float ib[512];
    int t = threadIdx.x;
    ib[t] = i_b[t]; ib[t + 256] = i_b[t + 256];
    __syncthreads();
    int o = blockIdx.x * 256 + t;
    float acc = o_b[o];
    const float* row = o_w + (size_t)o * 512;
    for (int k = 0; k < 512; ++k) acc += row[k] * ib[k];
    v[o] = acc;
}

// wu[l] = sum_k c_b[k] * s_w[k,l]
__global__ void __launch_bounds__(256) wu_kernel(
    const float* __restrict__ s_w, const float* __restrict__ c_b,
    float* __restrict__ wu)
{
    __shared__ float cb[512];
    int t = threadIdx.x;
    cb[t] = c_b[t]; cb[t + 256] = c_b[t + 256];
    __syncthreads();
    int l = blockIdx.x * 256 + t;
    float acc = 0.f;
    for (int k = 0; k < 512; ++k) acc += cb[k] * s_w[(size_t)k * 512 + l];
    wu[l] = acc;
}

// u[r] = sum_l snT[r,l] * wu[l]   (r over B*4096 rows; 1 wave per row)
__global__ void __launch_bounds__(256) rowdot_kernel(
    const u16* __restrict__ snT, const float* __restrict__ wu,
    float* __restrict__ u)
{
    __shared__ float swu[512];
    int t = threadIdx.x;
    swu[t] = wu[t]; swu[t + 256] = wu[t + 256];
    __syncthreads();
    int lane = t & 63, wv = t >> 6;
    int row = blockIdx.x * 4 + wv;
    u16x8v h = *(const u16x8v*)(snT + (size_t)row * 512 + lane * 8);
    float acc = 0.f;
#pragma unroll
    for (int i = 0; i < 8; ++i) acc += h2f(h[i]) * swu[lane * 8 + i];
#pragma unroll
    for (int m = 1; m < 64; m <<= 1) acc += __shfl_xor(acc, m);
    if (!lane) u[row] = acc;
}

// ---------------------------------------------------------------- GEMM ----
// C[i,j] = sum_k A[i,k]*B[j,k]  (A:[M,ldk] rowmajor, B:[N,ldk] rowmajor),
// K steps of the k loop. z decomposes as batch = z/zdiv, chunk = z%zdiv:
//   A += batch*aBatch + chunk*aChunk;  B += batch*bBatch + chunk*bChunk;
//   out += z*oZ; resid += z*rZ.   bias nullable.
#define EPI_F32       0
#define EPI_T_F16     1
#define EPI_PLAIN_F16 2
#define EPI_OUT       3

__device__ __forceinline__ void stage_tile(
    const u16* __restrict__ g, int ldk, int i0, int k0, char* tile, int wv, int lane)
{
#pragma unroll
    for (int cc = 0; cc < 4; ++cc) {
        int chunk = (wv * 4 + cc) * 64 + lane;   // 16B-chunk linear index in tile
        int row  = chunk >> 3;                   // 8 chunks (128B) per row
        int slot = chunk & 7;
        int gc   = slot ^ (row & 7);             // pre-swizzled source column-chunk
        const u16* gp = g + (size_t)(i0 + row) * ldk + (k0 + gc * 8);
        char* lp = tile + (size_t)(wv * 4 + cc) * 1024; // wave-uniform base
        __builtin_amdgcn_global_load_lds(
            (const __attribute__((address_space(1))) unsigned int*)gp,
            (__attribute__((address_space(3))) unsigned int*)lp, 16, 0, 0);
    }
}

template<int EPI>
__global__ void __launch_bounds__(256) gemm_bt(
    const u16* __restrict__ A_, const u16* __restrict__ B_,
    int K, int ldk, const float* __restrict__ bias,
    float* __restrict__ outF_, u16* __restrict__ outH_,
    const float* __restrict__ resid_, int ldo, int zdiv,
    long aBatch, long aChunk, long bBatch, long bChunk, long oZ, long rZ)
{
    __shared__ char smem[32768];
    char* sA = smem;
    char* sB = smem + 16384;

    int bz = blockIdx.z;
    int batch = bz / zdiv, chunk = bz % zdiv;
    const u16* A  = A_ + (size_t)batch * aBatch + (size_t)chunk * aChunk;
    const u16* Bm = B_ + (size_t)batch * bBatch + (size_t)chunk * bChunk;

    int i0 = blockIdx.y * 128, j0 = blockIdx.x * 128;
    int tid = threadIdx.x, lane = tid & 63, wv = tid >> 6;
    int wr = wv >> 1, wc = wv & 1;
    int r15 = lane & 15, h4 = lane >> 4;

    f32x4 zero = {0.f, 0.f, 0.f, 0.f};
    f32x4 acc[4][4];
#pragma unroll
    for (int m = 0; m < 4; ++m)
#pragma unroll
        for (int n = 0; n < 4; ++n) acc[m][n] = zero;

    for (int k0 = 0; k0 < K; k0 += 64) {
        stage_tile(A, ldk, i0, k0, sA, wv, lane);
        stage_tile(Bm, ldk, j0, k0, sB, wv, lane);
        asm volatile("s_waitcnt vmcnt(0)" ::: "memory");
        __syncthreads();
#pragma unroll
        for (int ks = 0; ks < 2; ++ks) {
            f16x8 a[4], b[4];
#pragma unroll
            for (int m = 0; m < 4; ++m) {
                int row = wr * 64 + m * 16 + r15;
                int off = row * 128 + (((ks * 4 + h4) ^ (row & 7)) << 4);
                a[m] = *(const f16x8*)(sA + off);
            }
#pragma unroll
            for (int n = 0; n < 4; ++n) {
                int col = wc * 64 + n * 16 + r15;
                int off = col * 128 + (((ks * 4 + h4) ^ (col & 7)) << 4);
                b[n] = *(const f16x8*)(sB + off);
            }
#pragma unroll
            for (int m = 0; m < 4; ++m)
#pragma unroll
                for (int n = 0; n < 4; ++n)
                    acc[m][n] = __builtin_amdgcn_mfma_f32_16x16x32_f16(a[m], b[n], acc[m][n], 0, 0, 0);
        }
        __syncthreads();
    }

    float* outF = outF_ ? outF_ + (size_t)bz * oZ : nullptr;
    u16* outH = outH_ ? outH_ + (size_t)bz * oZ : nullptr;
    const float* resid = resid_ ? resid_ + (size_t)bz * rZ : nullptr;

#pragma unroll
    for (int m = 0; m < 4; ++m)
#pragma unroll
        for (int n = 0; n < 4; ++n) {
            int ibase = i0 + wr * 64 + m * 16 + h4 * 4;
            int j = j0 + wc * 64 + n * 16 + r15;
#pragma unroll
            for (int r = 0; r < 4; ++r) {
                int i = ibase + r;
                float v = acc[m][n][r];
                if constexpr (EPI == EPI_T_F16 || EPI == EPI_PLAIN_F16 || EPI == EPI_OUT)
                    if (bias) v += bias[i];
                if constexpr (EPI == EPI_F32) {
                    outF[(size_t)i * ldo + j] = v;
                } else if constexpr (EPI == EPI_T_F16) {
                    outH[(size_t)j * ldo + i] = f2h(v);
                } else if constexpr (EPI == EPI_PLAIN_F16) {
                    outH[(size_t)i * ldo + j] = f2h(v);
                } else { // EPI_OUT
                    outF[(size_t)i * ldo + j] = v + resid[(size_t)i * ldo + j];
                }
            }
        }
}

// ------------------------------------------------------ softmax (f16) ----
// one block per row; L row f16[4096] += u[col], softmax over m, IN PLACE
__global__ void __launch_bounds__(256) softmax16(
    u16* __restrict__ LP, const float* __restrict__ u)
{
    u16x8v* row = (u16x8v*)(LP + (size_t)blockIdx.x * 4096);
    const float4* u4 = (const float4*)u;
    int t = threadIdx.x, lane = t & 63, wv = t >> 6;
    u16x8v ca = row[t], cb = row[t + 256];
    float4 ua0 = u4[2 * t], ua1 = u4[2 * t + 1];
    float4 ub0 = u4[2 * (t + 256)], ub1 = u4[2 * (t + 256) + 1];
    float va[8], vb[8];
    va[0] = h2f(ca[0]) + ua0.x; va[1] = h2f(ca[1]) + ua0.y;
    va[2] = h2f(ca[2]) + ua0.z; va[3] = h2f(ca[3]) + ua0.w;
    va[4] = h2f(ca[4]) + ua1.x; va[5] = h2f(ca[5]) + ua1.y;
    va[6] = h2f(ca[6]) + ua1.z; va[7] = h2f(ca[7]) + ua1.w;
    vb[0] = h2f(cb[0]) + ub0.x; vb[1] = h2f(cb[1]) + ub0.y;
    vb[2] = h2f(cb[2]) + ub0.z; vb[3] = h2f(cb[3]) + ub0.w;
    vb[4] = h2f(cb[4]) + ub1.x; vb[5] = h2f(cb[5]) + ub1.y;
    vb[6] = h2f(cb[6]) + ub1.z; vb[7] = h2f(cb[7]) + ub1.w;
    float mx = -3.4e38f;
#pragma unroll
    for (int i = 0; i < 8; ++i) mx = fmaxf(mx, fmaxf(va[i], vb[i]));
#pragma unroll
    for (int m = 1; m < 64; m <<= 1) mx = fmaxf(mx, __shfl_xor(mx, m));
    __shared__ float sM[4], sS[4];
    if (!lane) sM[wv] = mx;
    __syncthreads();
    mx = fmaxf(fmaxf(sM[0], sM[1]), fmaxf(sM[2], sM[3]));
    float sum = 0.f;
#pragma unroll
    for (int i = 0; i < 8; ++i) {
        va[i] = __expf(va[i] - mx);
        vb[i] = __expf(vb[i] - mx);
        sum += va[i] + vb[i];
    }
#pragma unroll
    for (int m = 1; m < 64; m <<= 1) sum += __shfl_xor(sum, m);
    if (!lane) sS[wv] = sum;
    __syncthreads();
    sum = sS[0] + sS[1] + sS[2] + sS[3];
    float inv = 1.0f / sum;
    u16x8v oa, ob;
#pragma unroll
    for (int i = 0; i < 8; ++i) {
        oa[i] = f2h(va[i] * inv);
        ob[i] = f2h(vb[i] * inv);
    }
    row[t] = oa; row[t + 256] = ob;
}

// ------------------------------------------------------ split-K reduce ----
// part: [4][4096][512] fp32 -> smT [4096,512] f16 (elementwise 4-plane sum)
__global__ void __launch_bounds__(256) reduce4_kernel(
    const float* __restrict__ part, u16* __restrict__ smT)
{
    const size_t P4 = 2097152 / 4;           // float4 per plane
    size_t g = (size_t)blockIdx.x * 256 + threadIdx.x;
    const float4* p = (const float4*)part;
    float4 v = p[g];
    float4 v1 = p[g + P4], v2 = p[g + 2 * P4], v3 = p[g + 3 * P4];
    v.x += v1.x + v2.x + v3.x; v.y += v1.y + v2.y + v3.y;
    v.z += v1.z + v2.z + v3.z; v.w += v1.w + v2.w + v3.w;
    u16x4 o;
    o[0] = f2h(v.x); o[1] = f2h(v.y); o[2] = f2h(v.z); o[3] = f2h(v.w);
    *(u16x4*)(smT + g * 4) = o;
}

// -------------------------------------------------------------- launch ----
extern "C" void kernel_launch(void* const* d_in, const int* in_sizes, int n_in,
                              void* d_out, int out_size, void* d_ws, size_t ws_size,
                              hipStream_t stream)
{
    const float* c   = (const float*)d_in[0];
    const float* s   = (const float*)d_in[1];
    const float* x   = (const float*)d_in[2];
    const float* c_w = (const float*)d_in[3];
    const float* c_b = (const float*)d_in[4];
    const float* s_w = (const float*)d_in[5];
    const float* s_b = (const float*)d_in[6];
    const float* i_w = (const float*)d_in[7];
    const float* i_b = (const float*)d_in[8];
    const float* o_w = (const float*)d_in[9];
    const float* o_b = (const float*)d_in[10];
    float* out = (float*)d_out;
    char* ws = (char*)d_ws;

    const int B = 4, C = 512, N = 4096;
    const size_t NC = (size_t)N * C;          // 2097152
    const size_t W2 = (size_t)C * C;          // 262144
    const size_t NN = (size_t)N * N;          // 16777216

    size_t off = 0;
    auto alloc = [&](size_t bytes) { size_t o = off; off += (bytes + 255) & ~(size_t)255; return o; };

    size_t o_meanC = alloc((size_t)B * C * 4);
    size_t o_rstdC = alloc((size_t)B * C * 4);
    size_t o_meanS = alloc((size_t)B * C * 4);
    size_t o_rstdS = alloc((size_t)B * C * 4);
    size_t o_cwT = alloc(W2 * 2);
    size_t o_swT = alloc(W2 * 2);
    size_t o_iwT = alloc(W2 * 2);
    size_t o_ow  = alloc(W2 * 2);
    size_t o_G   = alloc(W2 * 2);            // G = c_w^T @ s_w, f16
    size_t o_W   = alloc(W2 * 2);            // W = o_w @ i_w, f16
    size_t o_v   = alloc((size_t)C * 4);     // v = o_w@i_b + o_b
    size_t o_wu  = alloc((size_t)C * 4);     // wu = s_w^T c_b
    size_t o_u   = alloc((size_t)B * N * 4); // u[b,m]
    size_t o_cnT = alloc(B * NC * 2);        // normalized c, transposed
    size_t o_snT = alloc(B * NC * 2);        // normalized s, transposed -> smT later
    size_t o_sgT = alloc(B * NC * 2);        // sg = G @ sn, transposed
    size_t o_sR  = alloc(B * NC * 2);        // raw s f16 [B,C,N]
    size_t o_P   = alloc(NN * 2);            // per-batch logits/P f16 (33.5MB)
    size_t o_pt  = alloc(4 * NC * 4);        // per-batch split-K4 partials fp32

    if (ws_size < off) { // not enough scratch: bail (will fail check loudly)
        hipMemsetAsync(d_out, 0, (size_t)out_size * 4, stream);
        return;
    }

    float* meanC = (float*)(ws + o_meanC);
    float* rstdC = (float*)(ws + o_rstdC);
    float* meanS = (float*)(ws + o_meanS);
    float* rstdS = (float*)(ws + o_rstdS);
    u16* cwT = (u16*)(ws + o_cwT);
    u16* swT = (u16*)(ws + o_swT);
    u16* iwT = (u16*)(ws + o_iwT);
    u16* ow  = (u16*)(ws + o_ow);
    u16* Gf  = (u16*)(ws + o_G);
    u16* Wf  = (u16*)(ws + o_W);
    float* vb = (float*)(ws + o_v);
    float* wu = (float*)(ws + o_wu);
    float* ub = (float*)(ws + o_u);
    u16* cnT = (u16*)(ws + o_cnT);
    u16* snT = (u16*)(ws + o_snT);
    u16* sgT = (u16*)(ws + o_sgT);
    u16* sR  = (u16*)(ws + o_sR);
    u16* Pb  = (u16*)(ws + o_P);
    float* part = (float*)(ws + o_pt);
    u16* smT = snT;                          // reuse snT after sg conv + rowdot

    // 1) instance-norm stats
    stats_kernel<<<dim3(B * C, 2), 256, 0, stream>>>(c, s, meanC, rstdC, meanS, rstdS);
    // 2) packs: c -> cnT (norm,T); s -> snT (norm,T) + sR (raw, natural)
    pack_kernel<0><<<dim3(N / 32, C / 32, B), dim3(32, 8), 0, stream>>>(c, meanC, rstdC, cnT, nullptr);
    pack_kernel<3><<<dim3(N / 32, C / 32, B), dim3(32, 8), 0, stream>>>(s, meanS, rstdS, snT, sR);
    // 3) weight preps
    tpack512<<<dim3(16, 16), dim3(32, 8), 0, stream>>>(c_w, cwT);
    tpack512<<<dim3(16, 16), dim3(32, 8), 0, stream>>>(s_w, swT);
    tpack512<<<dim3(16, 16), dim3(32, 8), 0, stream>>>(i_w, iwT);
    split_f16<<<dim3((int)(W2 / 256)), 256, 0, stream>>>(o_w, ow, (int)W2);
    vbias_kernel<<<dim3(2), 256, 0, stream>>>(o_w, i_b, o_b, vb);
    wu_kernel<<<dim3(2), 256, 0, stream>>>(s_w, c_b, wu);
    // G[a,l] = sum_k c_w[k,a]*s_w[k,l]
    gemm_bt<EPI_PLAIN_F16><<<dim3(4, 4, 1), 256, 0, stream>>>(
        cwT, swT, 512, 512, nullptr, nullptr, Gf, nullptr, 512, 1,
        0, 0, 0, 0, 0, 0);
    // W = o_w @ i_w
    gemm_bt<EPI_PLAIN_F16><<<dim3(4, 4, 1), 256, 0, stream>>>(
        ow, iwT, 512, 512, nullptr, nullptr, Wf, nullptr, 512, 1,
        0, 0, 0, 0, 0, 0);
    // 4) sg = G @ sn -> sgT [B,N,C] f16
    gemm_bt<EPI_T_F16><<<dim3(32, 4, B), 256, 0, stream>>>(
        Gf, snT, 512, 512, nullptr, nullptr, sgT, nullptr, 512, 1,
        0, 0, (long)NC, 0, (long)NC, 0);
    // 5) u[b,m] = sum_l snT[b,m,l]*wu[l]
    rowdot_kernel<<<dim3(B * N / 4), 256, 0, stream>>>(snT, wu, ub);
    // 6) per-batch attention (P stays L3-resident)
    for (int b = 0; b < B; ++b) {
        // logits L[n,m] = sum_a cnT[n,a]*sgT[m,a] -> Pb f16
        gemm_bt<EPI_PLAIN_F16><<<dim3(32, 32, 1), 256, 0, stream>>>(
            cnT + (size_t)b * NC, sgT + (size_t)b * NC,
            512, 512, nullptr, nullptr, Pb, nullptr, 4096, 1,
            0, 0, 0, 0, 0, 0);
        // P = softmax_m(L + u[m]) in place
        softmax16<<<dim3(N), 256, 0, stream>>>(Pb, ub + (size_t)b * N);
        // sm[n,c] = sum_m P[n,m]*sR[c,m], split-K4 fp32 partials
        gemm_bt<EPI_F32><<<dim3(4, 32, 4), 256, 0, stream>>>(
            Pb, sR + (size_t)b * NC, 1024, 4096, nullptr,
            part, nullptr, nullptr, 512, 4,
            0, 1024L, 0, 1024L, (long)NC, 0);
        // reduce 4 planes -> smT_b [N,C] f16
        reduce4_kernel<<<dim3((int)(NC / 1024)), 256, 0, stream>>>(
            part, smT + (size_t)b * NC);
    }
    // 7) out = x + W @ sm + v
    gemm_bt<EPI_OUT><<<dim3(32, 4, B), 256, 0, stream>>>(
        Wf, smT, 512, 512, vb, out, nullptr, x, 4096, 1,
        0, 0, (long)NC, 0, (long)NC, (long)NC);
}

// Round 7
// 488.061 us; speedup vs baseline: 1.0295x; 1.0295x over previous
//
#include <hip/hip_runtime.h>

typedef unsigned short u16;
typedef _Float16 f16x8 __attribute__((ext_vector_type(8)));
typedef float f32x4 __attribute__((ext_vector_type(4)));
typedef u16 u16x4 __attribute__((ext_vector_type(4)));
typedef u16 u16x8v __attribute__((ext_vector_type(8)));

__device__ __forceinline__ u16 f2h(float f) {
    _Float16 h = (_Float16)f;
    return __builtin_bit_cast(u16, h);
}
__device__ __forceinline__ float h2f(u16 u) {
    return (float)__builtin_bit_cast(_Float16, u);
}

// ---------------------------------------------------------------- stats ----
__global__ void __launch_bounds__(256) stats_kernel(
    const float* __restrict__ c, const float* __restrict__ s,
    float* __restrict__ mC, float* __restrict__ rC,
    float* __restrict__ mS, float* __restrict__ rS)
{
    const float* src = (blockIdx.y ? s : c) + (size_t)blockIdx.x * 4096;
    int t = threadIdx.x, lane = t & 63, wv = t >> 6;
    const float4* p = (const float4*)src;
    float sum = 0.f, sq = 0.f;
#pragma unroll
    for (int i = 0; i < 4; ++i) {
        float4 v = p[t + 256 * i];
        sum += v.x + v.y + v.z + v.w;
        sq  += v.x * v.x + v.y * v.y + v.z * v.z + v.w * v.w;
    }
#pragma unroll
    for (int m = 1; m < 64; m <<= 1) {
        sum += __shfl_xor(sum, m);
        sq  += __shfl_xor(sq, m);
    }
    __shared__ float sa[4], sb[4];
    if (!lane) { sa[wv] = sum; sb[wv] = sq; }
    __syncthreads();
    if (t == 0) {
        float S = sa[0] + sa[1] + sa[2] + sa[3];
        float Q = sb[0] + sb[1] + sb[2] + sb[3];
        float mean = S * (1.0f / 4096.0f);
        float var = (Q - 4096.0f * mean * mean) * (1.0f / 4095.0f);
        float rstd = rsqrtf(var + 1e-5f);
        if (blockIdx.y) { mS[blockIdx.x] = mean; rS[blockIdx.x] = rstd; }
        else            { mC[blockIdx.x] = mean; rC[blockIdx.x] = rstd; }
    }
}

// ------------------------------------------------------- transpose pack ----
// MODE 0: dh = transposed normalized [B,N,C] f16.
// MODE 3: dh = transposed normalized; dl = NATURAL raw [B,C,N] f16.
template<int MODE>
__global__ void __launch_bounds__(256) pack_kernel(
    const float* __restrict__ src, const float* __restrict__ mean,
    const float* __restrict__ rstd, u16* __restrict__ dh, u16* __restrict__ dl)
{
    __shared__ float tile[32][33];
    int b = blockIdx.z, n0 = blockIdx.x * 32, c0 = blockIdx.y * 32;
    int tx = threadIdx.x, ty = threadIdx.y;
    const float* sbp = src + ((size_t)b * 512 + c0) * 4096 + n0;
#pragma unroll
    for (int it = 0; it < 4; ++it) {
        int cc = ty + it * 8;
        float v = sbp[(size_t)cc * 4096 + tx];
        tile[cc][tx] = v;
        if (MODE == 3)
            dl[((size_t)b * 512 + c0 + cc) * 4096 + n0 + tx] = f2h(v);
    }
    __syncthreads();
    int ch = c0 + tx;
    float mn = mean[b * 512 + ch];
    float rs = rstd[b * 512 + ch];
    size_t obase = ((size_t)b * 4096 + n0) * 512 + c0;
#pragma unroll
    for (int it = 0; it < 4; ++it) {
        int r = ty + it * 8;
        dh[obase + (size_t)r * 512 + tx] = f2h((tile[tx][r] - mn) * rs);
    }
}

// ------------------------------------------------------------ wt packs ----
__global__ void __launch_bounds__(256) split_f16(
    const float* __restrict__ src, u16* __restrict__ h, int n)
{
    int i = blockIdx.x * 256 + threadIdx.x;
    if (i < n) h[i] = f2h(src[i]);
}

// wT[c][k] = w[k][c], 512x512 fp32 -> f16
__global__ void __launch_bounds__(256) tpack512(
    const float* __restrict__ w, u16* __restrict__ wT)
{
    __shared__ float tile[32][33];
    int c0 = blockIdx.x * 32, k0 = blockIdx.y * 32;
    int tx = threadIdx.x, ty = threadIdx.y;
#pragma unroll
    for (int it = 0; it < 4; ++it) {
        int kk = ty + it * 8;
        tile[kk][tx] = w[(size_t)(k0 + kk) * 512 + c0 + tx];
    }
    __syncthreads();
#pragma unroll
    for (int it = 0; it < 4; ++it) {
        int r = ty + it * 8;
        wT[(size_t)(c0 + r) * 512 + k0 + tx] = f2h(tile[tx][r]);
    }
}

// v[o] = o_b[o] + sum_k o_w[o,k] * i_b[k]   (fp32 inputs)
__global__ void __launch_bounds__(256) vbias_kernel(
    const float* __restrict__ o_w, const float* __restrict__ i_b,
    const float* __restrict__ o_b, float* __restrict__ v)
{
    __shared__ float ib[512];
    int t = threadIdx.x;
    ib[t] = i_b[t]; ib[t + 256] = i_b[t + 256];
    __syncthreads();
    int o = blockIdx.x * 256 + t;
    float acc = o_b[o];
    const float* row = o_w + (size_t)o * 512;
    for (int k = 0; k < 512; ++k) acc += row[k] * ib[k];
    v[o] = acc;
}

// wu[l] = sum_k c_b[k] * s_w[k,l]
__global__ void __launch_bounds__(256) wu_kernel(
    const float* __restrict__ s_w, const float* __restrict__ c_b,
    float* __restrict__ wu)
{
    __shared__ float cb[512];
    int t = threadIdx.x;
    cb[t] = c_b[t]; cb[t + 256] = c_b[t + 256];
    __syncthreads();
    int l = blockIdx.x * 256 + t;
    float acc = 0.f;
    for (int k = 0; k < 512; ++k) acc += cb[k] * s_w[(size_t)k * 512 + l];
    wu[l] = acc;
}

// u[r] = sum_l snT[r,l] * wu[l]   (r over B*4096 rows; 1 wave per row)
__global__ void __launch_bounds__(256) rowdot_kernel(
    const u16* __restrict__ snT, const float* __restrict__ wu,
    float* __restrict__ u)
{
    __shared__ float swu[512];
    int t = threadIdx.x;
    swu[t] = wu[t]; swu[t + 256] = wu[t + 256];
    __syncthreads();
    int lane = t & 63, wv = t >> 6;
    int row = blockIdx.x * 4 + wv;
    u16x8v h = *(const u16x8v*)(snT + (size_t)row * 512 + lane * 8);
    float acc = 0.f;
#pragma unroll
    for (int i = 0; i < 8; ++i) acc += h2f(h[i]) * swu[lane * 8 + i];
#pragma unroll
    for (int m = 1; m < 64; m <<= 1) acc += __shfl_xor(acc, m);
    if (!lane) u[row] = acc;
}

// ---------------------------------------------------------------- GEMM ----
// C[i,j] = sum_k A[i,k]*B[j,k]  (A:[M,ldk] rowmajor, B:[N,ldk] rowmajor),
// K steps of the k loop. z decomposes as batch = z/zdiv, chunk = z%zdiv:
//   A += batch*aBatch + chunk*aChunk;  B += batch*bBatch + chunk*bChunk;
//   out += z*oZ; resid += z*rZ.   bias nullable.
#define EPI_F32       0
#define EPI_T_F16     1
#define EPI_PLAIN_F16 2
#define EPI_OUT       3

__device__ __forceinline__ void stage_tile(
    const u16* __restrict__ g, int ldk, int i0, int k0, char* tile, int wv, int lane)
{
#pragma unroll
    for (int cc = 0; cc < 4; ++cc) {
        int chunk = (wv * 4 + cc) * 64 + lane;   // 16B-chunk linear index in tile
        int row  = chunk >> 3;                   // 8 chunks (128B) per row
        int slot = chunk & 7;
        int gc   = slot ^ (row & 7);             // pre-swizzled source column-chunk
        const u16* gp = g + (size_t)(i0 + row) * ldk + (k0 + gc * 8);
        char* lp = tile + (size_t)(wv * 4 + cc) * 1024; // wave-uniform base
        __builtin_amdgcn_global_load_lds(
            (const __attribute__((address_space(1))) unsigned int*)gp,
            (__attribute__((address_space(3))) unsigned int*)lp, 16, 0, 0);
    }
}

template<int EPI>
__global__ void __launch_bounds__(256) gemm_bt(
    const u16* __restrict__ A_, const u16* __restrict__ B_,
    int K, int ldk, const float* __restrict__ bias,
    float* __restrict__ outF_, u16* __restrict__ outH_,
    const float* __restrict__ resid_, int ldo, int zdiv,
    long aBatch, long aChunk, long bBatch, long bChunk, long oZ, long rZ)
{
    __shared__ char smem[32768];
    char* sA = smem;
    char* sB = smem + 16384;

    int bz = blockIdx.z;
    int batch = bz / zdiv, chunk = bz % zdiv;
    const u16* A  = A_ + (size_t)batch * aBatch + (size_t)chunk * aChunk;
    const u16* Bm = B_ + (size_t)batch * bBatch + (size_t)chunk * bChunk;

    int i0 = blockIdx.y * 128, j0 = blockIdx.x * 128;
    int tid = threadIdx.x, lane = tid & 63, wv = tid >> 6;
    int wr = wv >> 1, wc = wv & 1;
    int r15 = lane & 15, h4 = lane >> 4;

    f32x4 zero = {0.f, 0.f, 0.f, 0.f};
    f32x4 acc[4][4];
#pragma unroll
    for (int m = 0; m < 4; ++m)
#pragma unroll
        for (int n = 0; n < 4; ++n) acc[m][n] = zero;

    for (int k0 = 0; k0 < K; k0 += 64) {
        stage_tile(A, ldk, i0, k0, sA, wv, lane);
        stage_tile(Bm, ldk, j0, k0, sB, wv, lane);
        asm volatile("s_waitcnt vmcnt(0)" ::: "memory");
        __syncthreads();
#pragma unroll
        for (int ks = 0; ks < 2; ++ks) {
            f16x8 a[4], b[4];
#pragma unroll
            for (int m = 0; m < 4; ++m) {
                int row = wr * 64 + m * 16 + r15;
                int off = row * 128 + (((ks * 4 + h4) ^ (row & 7)) << 4);
                a[m] = *(const f16x8*)(sA + off);
            }
#pragma unroll
            for (int n = 0; n < 4; ++n) {
                int col = wc * 64 + n * 16 + r15;
                int off = col * 128 + (((ks * 4 + h4) ^ (col & 7)) << 4);
                b[n] = *(const f16x8*)(sB + off);
            }
#pragma unroll
            for (int m = 0; m < 4; ++m)
#pragma unroll
                for (int n = 0; n < 4; ++n)
                    acc[m][n] = __builtin_amdgcn_mfma_f32_16x16x32_f16(a[m], b[n], acc[m][n], 0, 0, 0);
        }
        __syncthreads();
    }

    float* outF = outF_ ? outF_ + (size_t)bz * oZ : nullptr;
    u16* outH = outH_ ? outH_ + (size_t)bz * oZ : nullptr;
    const float* resid = resid_ ? resid_ + (size_t)bz * rZ : nullptr;

#pragma unroll
    for (int m = 0; m < 4; ++m)
#pragma unroll
        for (int n = 0; n < 4; ++n) {
            int ibase = i0 + wr * 64 + m * 16 + h4 * 4;
            int j = j0 + wc * 64 + n * 16 + r15;
#pragma unroll
            for (int r = 0; r < 4; ++r) {
                int i = ibase + r;
                float v = acc[m][n][r];
                if constexpr (EPI == EPI_T_F16 || EPI == EPI_PLAIN_F16 || EPI == EPI_OUT)
                    if (bias) v += bias[i];
                if constexpr (EPI == EPI_F32) {
                    outF[(size_t)i * ldo + j] = v;
                } else if constexpr (EPI == EPI_T_F16) {
                    outH[(size_t)j * ldo + i] = f2h(v);
                } else if constexpr (EPI == EPI_PLAIN_F16) {
                    outH[(size_t)i * ldo + j] = f2h(v);
                } else { // EPI_OUT
                    outF[(size_t)i * ldo + j] = v + resid[(size_t)i * ldo + j];
                }
            }
        }
}

// ------------------------------------------------------ softmax (f16) ----
// one block per row; L row f16[4096] += u[col], softmax over m, IN PLACE
__global__ void __launch_bounds__(256) softmax16(
    u16* __restrict__ LP, const float* __restrict__ u)
{
    u16x8v* row = (u16x8v*)(LP + (size_t)blockIdx.x * 4096);
    const float4* u4 = (const float4*)u;
    int t = threadIdx.x, lane = t & 63, wv = t >> 6;
    u16x8v ca = row[t], cb = row[t + 256];
    float4 ua0 = u4[2 * t], ua1 = u4[2 * t + 1];
    float4 ub0 = u4[2 * (t + 256)], ub1 = u4[2 * (t + 256) + 1];
    float va[8], vb[8];
    va[0] = h2f(ca[0]) + ua0.x; va[1] = h2f(ca[1]) + ua0.y;
    va[2] = h2f(ca[2]) + ua0.z; va[3] = h2f(ca[3]) + ua0.w;
    va[4] = h2f(ca[4]) + ua1.x; va[5] = h2f(ca[5]) + ua1.y;
    va[6] = h2f(ca[6]) + ua1.z; va[7] = h2f(ca[7]) + ua1.w;
    vb[0] = h2f(cb[0]) + ub0.x; vb[1] = h2f(cb[1]) + ub0.y;
    vb[2] = h2f(cb[2]) + ub0.z; vb[3] = h2f(cb[3]) + ub0.w;
    vb[4] = h2f(cb[4]) + ub1.x; vb[5] = h2f(cb[5]) + ub1.y;
    vb[6] = h2f(cb[6]) + ub1.z; vb[7] = h2f(cb[7]) + ub1.w;
    float mx = -3.4e38f;
#pragma unroll
    for (int i = 0; i < 8; ++i) mx = fmaxf(mx, fmaxf(va[i], vb[i]));
#pragma unroll
    for (int m = 1; m < 64; m <<= 1) mx = fmaxf(mx, __shfl_xor(mx, m));
    __shared__ float sM[4], sS[4];
    if (!lane) sM[wv] = mx;
    __syncthreads();
    mx = fmaxf(fmaxf(sM[0], sM[1]), fmaxf(sM[2], sM[3]));
    float sum = 0.f;
#pragma unroll
    for (int i = 0; i < 8; ++i) {
        va[i] = __expf(va[i] - mx);
        vb[i] = __expf(vb[i] - mx);
        sum += va[i] + vb[i];
    }
#pragma unroll
    for (int m = 1; m < 64; m <<= 1) sum += __shfl_xor(sum, m);
    if (!lane) sS[wv] = sum;
    __syncthreads();
    sum = sS[0] + sS[1] + sS[2] + sS[3];
    float inv = 1.0f / sum;
    u16x8v oa, ob;
#pragma unroll
    for (int i = 0; i < 8; ++i) {
        oa[i] = f2h(va[i] * inv);
        ob[i] = f2h(vb[i] * inv);
    }
    row[t] = oa; row[t + 256] = ob;
}

// ------------------------------------------------ split-K reduce + T ------
// part: [4][512][4096] fp32 (z-planes of sm[c,n]); out: smT [4096,512] f16
__global__ void __launch_bounds__(256) reduceT_kernel(
    const float* __restrict__ part, u16* __restrict__ smT)
{
    __shared__ float tile[32][33];
    int n0 = blockIdx.x * 32, c0 = blockIdx.y * 32;
    int tx = threadIdx.x, ty = threadIdx.y;
#pragma unroll
    for (int it = 0; it < 4; ++it) {
        int cc = ty + it * 8;
        size_t idx = (size_t)(c0 + cc) * 4096 + n0 + tx;
        float v = part[idx] + part[idx + 2097152] +
                  part[idx + 2 * 2097152] + part[idx + 3 * 2097152];
        tile[cc][tx] = v;
    }
    __syncthreads();
#pragma unroll
    for (int it = 0; it < 4; ++it) {
        int r = ty + it * 8;
        smT[(size_t)(n0 + r) * 512 + c0 + tx] = f2h(tile[tx][r]);
    }
}

// -------------------------------------------------------------- launch ----
extern "C" void kernel_launch(void* const* d_in, const int* in_sizes, int n_in,
                              void* d_out, int out_size, void* d_ws, size_t ws_size,
                              hipStream_t stream)
{
    const float* c   = (const float*)d_in[0];
    const float* s   = (const float*)d_in[1];
    const float* x   = (const float*)d_in[2];
    const float* c_w = (const float*)d_in[3];
    const float* c_b = (const float*)d_in[4];
    const float* s_w = (const float*)d_in[5];
    const float* s_b = (const float*)d_in[6];
    const float* i_w = (const float*)d_in[7];
    const float* i_b = (const float*)d_in[8];
    const float* o_w = (const float*)d_in[9];
    const float* o_b = (const float*)d_in[10];
    float* out = (float*)d_out;
    char* ws = (char*)d_ws;

    const int B = 4, C = 512, N = 4096;
    const size_t NC = (size_t)N * C;          // 2097152
    const size_t W2 = (size_t)C * C;          // 262144
    const size_t NN = (size_t)N * N;          // 16777216

    size_t off = 0;
    auto alloc = [&](size_t bytes) { size_t o = off; off += (bytes + 255) & ~(size_t)255; return o; };

    size_t o_meanC = alloc((size_t)B * C * 4);
    size_t o_rstdC = alloc((size_t)B * C * 4);
    size_t o_meanS = alloc((size_t)B * C * 4);
    size_t o_rstdS = alloc((size_t)B * C * 4);
    size_t o_cwT = alloc(W2 * 2);
    size_t o_swT = alloc(W2 * 2);
    size_t o_iwT = alloc(W2 * 2);
    size_t o_ow  = alloc(W2 * 2);
    size_t o_G   = alloc(W2 * 2);            // G = c_w^T @ s_w, f16
    size_t o_W   = alloc(W2 * 2);            // W = o_w @ i_w, f16
    size_t o_v   = alloc((size_t)C * 4);     // v = o_w@i_b + o_b
    size_t o_wu  = alloc((size_t)C * 4);     // wu = s_w^T c_b
    size_t o_u   = alloc((size_t)B * N * 4); // u[b,m]
    size_t o_cnT = alloc(B * NC * 2);        // normalized c, transposed
    size_t o_snT = alloc(B * NC * 2);        // normalized s, transposed -> smT later
    size_t o_sgT = alloc(B * NC * 2);        // sg = G @ sn, transposed
    size_t o_sR  = alloc(B * NC * 2);        // raw s f16 [B,C,N]
    size_t o_P   = alloc(NN * 2);            // per-batch logits/P f16 (33.5MB)
    size_t o_pt  = alloc(4 * NC * 4);        // per-batch split-K4 partials fp32

    if (ws_size < off) { // not enough scratch: bail (will fail check loudly)
        hipMemsetAsync(d_out, 0, (size_t)out_size * 4, stream);
        return;
    }

    float* meanC = (float*)(ws + o_meanC);
    float* rstdC = (float*)(ws + o_rstdC);
    float* meanS = (float*)(ws + o_meanS);
    float* rstdS = (float*)(ws + o_rstdS);
    u16* cwT = (u16*)(ws + o_cwT);
    u16* swT = (u16*)(ws + o_swT);
    u16* iwT = (u16*)(ws + o_iwT);
    u16* ow  = (u16*)(ws + o_ow);
    u16* Gf  = (u16*)(ws + o_G);
    u16* Wf  = (u16*)(ws + o_W);
    float* vb = (float*)(ws + o_v);
    float* wu = (float*)(ws + o_wu);
    float* ub = (float*)(ws + o_u);
    u16* cnT = (u16*)(ws + o_cnT);
    u16* snT = (u16*)(ws + o_snT);
    u16* sgT = (u16*)(ws + o_sgT);
    u16* sR  = (u16*)(ws + o_sR);
    u16* Pb  = (u16*)(ws + o_P);
    float* part = (float*)(ws + o_pt);
    u16* smT = snT;                          // reuse snT after sg conv + rowdot

    // 1) instance-norm stats
    stats_kernel<<<dim3(B * C, 2), 256, 0, stream>>>(c, s, meanC, rstdC, meanS, rstdS);
    // 2) packs: c -> cnT (norm,T); s -> snT (norm,T) + sR (raw, natural)
    pack_kernel<0><<<dim3(N / 32, C / 32, B), dim3(32, 8), 0, stream>>>(c, meanC, rstdC, cnT, nullptr);
    pack_kernel<3><<<dim3(N / 32, C / 32, B), dim3(32, 8), 0, stream>>>(s, meanS, rstdS, snT, sR);
    // 3) weight preps
    tpack512<<<dim3(16, 16), dim3(32, 8), 0, stream>>>(c_w, cwT);
    tpack512<<<dim3(16, 16), dim3(32, 8), 0, stream>>>(s_w, swT);
    tpack512<<<dim3(16, 16), dim3(32, 8), 0, stream>>>(i_w, iwT);
    split_f16<<<dim3((int)(W2 / 256)), 256, 0, stream>>>(o_w, ow, (int)W2);
    vbias_kernel<<<dim3(2), 256, 0, stream>>>(o_w, i_b, o_b, vb);
    wu_kernel<<<dim3(2), 256, 0, stream>>>(s_w, c_b, wu);
    // G[a,l] = sum_k c_w[k,a]*s_w[k,l]
    gemm_bt<EPI_PLAIN_F16><<<dim3(4, 4, 1), 256, 0, stream>>>(
        cwT, swT, 512, 512, nullptr, nullptr, Gf, nullptr, 512, 1,
        0, 0, 0, 0, 0, 0);
    // W = o_w @ i_w
    gemm_bt<EPI_PLAIN_F16><<<dim3(4, 4, 1), 256, 0, stream>>>(
        ow, iwT, 512, 512, nullptr, nullptr, Wf, nullptr, 512, 1,
        0, 0, 0, 0, 0, 0);
    // 4) sg = G @ sn -> sgT [B,N,C] f16
    gemm_bt<EPI_T_F16><<<dim3(32, 4, B), 256, 0, stream>>>(
        Gf, snT, 512, 512, nullptr, nullptr, sgT, nullptr, 512, 1,
        0, 0, (long)NC, 0, (long)NC, 0);
    // 5) u[b,m] = sum_l snT[b,m,l]*wu[l]
    rowdot_kernel<<<dim3(B * N / 4), 256, 0, stream>>>(snT, wu, ub);
    // 6) per-batch attention (P stays cache-resident)
    for (int b = 0; b < B; ++b) {
        // logits L[n,m] = sum_a cnT[n,a]*sgT[m,a] -> Pb f16
        gemm_bt<EPI_PLAIN_F16><<<dim3(32, 32, 1), 256, 0, stream>>>(
            cnT + (size_t)b * NC, sgT + (size_t)b * NC,
            512, 512, nullptr, nullptr, Pb, nullptr, 4096, 1,
            0, 0, 0, 0, 0, 0);
        // P = softmax_m(L + u[m]) in place
        softmax16<<<dim3(N), 256, 0, stream>>>(Pb, ub + (size_t)b * N);
        // sm[c,n] = sum_m sR[c,m]*P[n,m], split-K4: A = small V matrix,
        // B = big P swept x-fastest (R3's proven-fast orientation).
        gemm_bt<EPI_F32><<<dim3(32, 4, 4), 256, 0, stream>>>(
            sR + (size_t)b * NC, Pb, 1024, 4096, nullptr,
            part, nullptr, nullptr, 4096, 4,
            0, 1024L, 0, 1024L, (long)NC, 0);
        // reduce 4 planes + transpose -> smT_b [N,C] f16
        reduceT_kernel<<<dim3(128, 16), dim3(32, 8), 0, stream>>>(
            part, smT + (size_t)b * NC);
    }
    // 7) out = x + W @ sm + v
    gemm_bt<EPI_OUT><<<dim3(32, 4, B), 256, 0, stream>>>(
        Wf, smT, 512, 512, vb, out, nullptr, x, 4096, 1,
        0, 0, (long)NC, 0, (long)NC, (long)NC);
}

// Round 8
// 444.798 us; speedup vs baseline: 1.1297x; 1.0973x over previous
//
#include <hip/hip_runtime.h>

typedef unsigned short u16;
typedef _Float16 f16x8 __attribute__((ext_vector_type(8)));
typedef float f32x4 __attribute__((ext_vector_type(4)));
typedef u16 u16x8v __attribute__((ext_vector_type(8)));

__device__ __forceinline__ u16 f2h(float f) {
    _Float16 h = (_Float16)f;
    return __builtin_bit_cast(u16, h);
}
__device__ __forceinline__ float h2f(u16 u) {
    return (float)__builtin_bit_cast(_Float16, u);
}

// ---------------------------------------------------------------- stats ----
__global__ void __launch_bounds__(256) stats_kernel(
    const float* __restrict__ c, const float* __restrict__ s,
    float* __restrict__ mC, float* __restrict__ rC,
    float* __restrict__ mS, float* __restrict__ rS)
{
    const float* src = (blockIdx.y ? s : c) + (size_t)blockIdx.x * 4096;
    int t = threadIdx.x, lane = t & 63, wv = t >> 6;
    const float4* p = (const float4*)src;
    float sum = 0.f, sq = 0.f;
#pragma unroll
    for (int i = 0; i < 4; ++i) {
        float4 v = p[t + 256 * i];
        sum += v.x + v.y + v.z + v.w;
        sq  += v.x * v.x + v.y * v.y + v.z * v.z + v.w * v.w;
    }
#pragma unroll
    for (int m = 1; m < 64; m <<= 1) {
        sum += __shfl_xor(sum, m);
        sq  += __shfl_xor(sq, m);
    }
    __shared__ float sa[4], sb[4];
    if (!lane) { sa[wv] = sum; sb[wv] = sq; }
    __syncthreads();
    if (t == 0) {
        float S = sa[0] + sa[1] + sa[2] + sa[3];
        float Q = sb[0] + sb[1] + sb[2] + sb[3];
        float mean = S * (1.0f / 4096.0f);
        float var = (Q - 4096.0f * mean * mean) * (1.0f / 4095.0f);
        float rstd = rsqrtf(var + 1e-5f);
        if (blockIdx.y) { mS[blockIdx.x] = mean; rS[blockIdx.x] = rstd; }
        else            { mC[blockIdx.x] = mean; rC[blockIdx.x] = rstd; }
    }
}

// ------------------------------------------------------- transpose pack ----
// MODE 0: dh = transposed normalized [B,N,C] f16.
// MODE 2: dh = transposed normalized; dl = transposed RAW [B,N,C] f16.
template<int MODE>
__global__ void __launch_bounds__(256) pack_kernel(
    const float* __restrict__ src, const float* __restrict__ mean,
    const float* __restrict__ rstd, u16* __restrict__ dh, u16* __restrict__ dl)
{
    __shared__ float tile[32][33];
    int b = blockIdx.z, n0 = blockIdx.x * 32, c0 = blockIdx.y * 32;
    int tx = threadIdx.x, ty = threadIdx.y;
    const float* sbp = src + ((size_t)b * 512 + c0) * 4096 + n0;
#pragma unroll
    for (int it = 0; it < 4; ++it) {
        int cc = ty + it * 8;
        tile[cc][tx] = sbp[(size_t)cc * 4096 + tx];
    }
    __syncthreads();
    int ch = c0 + tx;
    float mn = mean[b * 512 + ch];
    float rs = rstd[b * 512 + ch];
    size_t obase = ((size_t)b * 4096 + n0) * 512 + c0;
#pragma unroll
    for (int it = 0; it < 4; ++it) {
        int r = ty + it * 8;
        float v = tile[tx][r];
        size_t o = obase + (size_t)r * 512 + tx;
        dh[o] = f2h((v - mn) * rs);
        if (MODE == 2) dl[o] = f2h(v);
    }
}

// ------------------------------------------------------------ wt packs ----
__global__ void __launch_bounds__(256) split_f16(
    const float* __restrict__ src, u16* __restrict__ h, int n)
{
    int i = blockIdx.x * 256 + threadIdx.x;
    if (i < n) h[i] = f2h(src[i]);
}

// wT[c][k] = w[k][c], 512x512 fp32 -> f16
__global__ void __launch_bounds__(256) tpack512(
    const float* __restrict__ w, u16* __restrict__ wT)
{
    __shared__ float tile[32][33];
    int c0 = blockIdx.x * 32, k0 = blockIdx.y * 32;
    int tx = threadIdx.x, ty = threadIdx.y;
#pragma unroll
    for (int it = 0; it < 4; ++it) {
        int kk = ty + it * 8;
        tile[kk][tx] = w[(size_t)(k0 + kk) * 512 + c0 + tx];
    }
    __syncthreads();
#pragma unroll
    for (int it = 0; it < 4; ++it) {
        int r = ty + it * 8;
        wT[(size_t)(c0 + r) * 512 + k0 + tx] = f2h(tile[tx][r]);
    }
}

// v[o] = o_b[o] + sum_k o_w[o,k] * i_b[k]   (fp32 inputs)
__global__ void __launch_bounds__(256) vbias_kernel(
    const float* __restrict__ o_w, const float* __restrict__ i_b,
    const float* __restrict__ o_b, float* __restrict__ v)
{
    __shared__ float ib[512];
    int t = threadIdx.x;
    ib[t] = i_b[t]; ib[t + 256] = i_b[t + 256];
    __syncthreads();
    int o = blockIdx.x * 256 + t;
    float acc = o_b[o];
    const float* row = o_w + (size_t)o * 512;
    for (int k = 0; k < 512; ++k) acc += row[k] * ib[k];
    v[o] = acc;
}

// wu[l] = sum_k c_b[k] * s_w[k,l]
__global__ void __launch_bounds__(256) wu_kernel(
    const float* __restrict__ s_w, const float* __restrict__ c_b,
    float* __restrict__ wu)
{
    __shared__ float cb[512];
    int t = threadIdx.x;
    cb[t] = c_b[t]; cb[t + 256] = c_b[t + 256];
    __syncthreads();
    int l = blockIdx.x * 256 + t;
    float acc = 0.f;
    for (int k = 0; k < 512; ++k) acc += cb[k] * s_w[(size_t)k * 512 + l];
    wu[l] = acc;
}

// u[r] = sum_l snT[r,l] * wu[l]   (r over B*4096 rows; 1 wave per row)
__global__ void __launch_bounds__(256) rowdot_kernel(
    const u16* __restrict__ snT, const float* __restrict__ wu,
    float* __restrict__ u)
{
    __shared__ float swu[512];
    int t = threadIdx.x;
    swu[t] = wu[t]; swu[t + 256] = wu[t + 256];
    __syncthreads();
    int lane = t & 63, wv = t >> 6;
    int row = blockIdx.x * 4 + wv;
    u16x8v h = *(const u16x8v*)(snT + (size_t)row * 512 + lane * 8);
    float acc = 0.f;
#pragma unroll
    for (int i = 0; i < 8; ++i) acc += h2f(h[i]) * swu[lane * 8 + i];
#pragma unroll
    for (int m = 1; m < 64; m <<= 1) acc += __shfl_xor(acc, m);
    if (!lane) u[row] = acc;
}

// ---------------------------------------------------------------- GEMM ----
// C[i,j] = sum_k A[i,k]*B[j,k]  (A:[M,ldk] rowmajor, B:[N,ldk] rowmajor),
// K steps of the k loop. z decomposes as batch = z/zdiv, chunk = z%zdiv:
//   A += batch*aBatch + chunk*aChunk;  B += batch*bBatch + chunk*bChunk;
//   out += z*oZ.   bias nullable.
#define EPI_F32       0
#define EPI_PLAIN_F16 2

__device__ __forceinline__ void stage_tile(
    const u16* __restrict__ g, int ldk, int i0, int k0, char* tile, int wv, int lane)
{
#pragma unroll
    for (int cc = 0; cc < 4; ++cc) {
        int chunk = (wv * 4 + cc) * 64 + lane;   // 16B-chunk linear index in tile
        int row  = chunk >> 3;                   // 8 chunks (128B) per row
        int slot = chunk & 7;
        int gc   = slot ^ (row & 7);             // pre-swizzled source column-chunk
        const u16* gp = g + (size_t)(i0 + row) * ldk + (k0 + gc * 8);
        char* lp = tile + (size_t)(wv * 4 + cc) * 1024; // wave-uniform base
        __builtin_amdgcn_global_load_lds(
            (const __attribute__((address_space(1))) unsigned int*)gp,
            (__attribute__((address_space(3))) unsigned int*)lp, 16, 0, 0);
    }
}

template<int EPI>
__global__ void __launch_bounds__(256) gemm_bt(
    const u16* __restrict__ A_, const u16* __restrict__ B_,
    int K, int ldk, const float* __restrict__ bias,
    float* __restrict__ outF_, u16* __restrict__ outH_,
    int ldo, int zdiv,
    long aBatch, long aChunk, long bBatch, long bChunk, long oZ)
{
    __shared__ char smem[32768];
    char* sA = smem;
    char* sB = smem + 16384;

    int bz = blockIdx.z;
    int batch = bz / zdiv, chunk = bz % zdiv;
    const u16* A  = A_ + (size_t)batch * aBatch + (size_t)chunk * aChunk;
    const u16* Bm = B_ + (size_t)batch * bBatch + (size_t)chunk * bChunk;

    int i0 = blockIdx.y * 128, j0 = blockIdx.x * 128;
    int tid = threadIdx.x, lane = tid & 63, wv = tid >> 6;
    int wr = wv >> 1, wc = wv & 1;
    int r15 = lane & 15, h4 = lane >> 4;

    f32x4 zero = {0.f, 0.f, 0.f, 0.f};
    f32x4 acc[4][4];
#pragma unroll
    for (int m = 0; m < 4; ++m)
#pragma unroll
        for (int n = 0; n < 4; ++n) acc[m][n] = zero;

    for (int k0 = 0; k0 < K; k0 += 64) {
        stage_tile(A, ldk, i0, k0, sA, wv, lane);
        stage_tile(Bm, ldk, j0, k0, sB, wv, lane);
        asm volatile("s_waitcnt vmcnt(0)" ::: "memory");
        __syncthreads();
#pragma unroll
        for (int ks = 0; ks < 2; ++ks) {
            f16x8 a[4], b[4];
#pragma unroll
            for (int m = 0; m < 4; ++m) {
                int row = wr * 64 + m * 16 + r15;
                int off = row * 128 + (((ks * 4 + h4) ^ (row & 7)) << 4);
                a[m] = *(const f16x8*)(sA + off);
            }
#pragma unroll
            for (int n = 0; n < 4; ++n) {
                int col = wc * 64 + n * 16 + r15;
                int off = col * 128 + (((ks * 4 + h4) ^ (col & 7)) << 4);
                b[n] = *(const f16x8*)(sB + off);
            }
#pragma unroll
            for (int m = 0; m < 4; ++m)
#pragma unroll
                for (int n = 0; n < 4; ++n)
                    acc[m][n] = __builtin_amdgcn_mfma_f32_16x16x32_f16(a[m], b[n], acc[m][n], 0, 0, 0);
        }
        __syncthreads();
    }

    float* outF = outF_ ? outF_ + (size_t)bz * oZ : nullptr;
    u16* outH = outH_ ? outH_ + (size_t)bz * oZ : nullptr;

#pragma unroll
    for (int m = 0; m < 4; ++m)
#pragma unroll
        for (int n = 0; n < 4; ++n) {
            int ibase = i0 + wr * 64 + m * 16 + h4 * 4;
            int j = j0 + wc * 64 + n * 16 + r15;
#pragma unroll
            for (int r = 0; r < 4; ++r) {
                int i = ibase + r;
                float v = acc[m][n][r];
                if constexpr (EPI == EPI_PLAIN_F16) {
                    if (bias) v += bias[i];
                    outH[(size_t)i * ldo + j] = f2h(v);
                } else { // EPI_F32
                    outF[(size_t)i * ldo + j] = v;
                }
            }
        }
}

// ------------------------------------------------------ softmax (f16) ----
// one block per row; L row f16[4096] += u[col], softmax over m, IN PLACE
__global__ void __launch_bounds__(256) softmax16(
    u16* __restrict__ LP, const float* __restrict__ u)
{
    u16x8v* row = (u16x8v*)(LP + (size_t)blockIdx.x * 4096);
    const float4* u4 = (const float4*)u;
    int t = threadIdx.x, lane = t & 63, wv = t >> 6;
    u16x8v ca = row[t], cb = row[t + 256];
    float4 ua0 = u4[2 * t], ua1 = u4[2 * t + 1];
    float4 ub0 = u4[2 * (t + 256)], ub1 = u4[2 * (t + 256) + 1];
    float va[8], vb[8];
    va[0] = h2f(ca[0]) + ua0.x; va[1] = h2f(ca[1]) + ua0.y;
    va[2] = h2f(ca[2]) + ua0.z; va[3] = h2f(ca[3]) + ua0.w;
    va[4] = h2f(ca[4]) + ua1.x; va[5] = h2f(ca[5]) + ua1.y;
    va[6] = h2f(ca[6]) + ua1.z; va[7] = h2f(ca[7]) + ua1.w;
    vb[0] = h2f(cb[0]) + ub0.x; vb[1] = h2f(cb[1]) + ub0.y;
    vb[2] = h2f(cb[2]) + ub0.z; vb[3] = h2f(cb[3]) + ub0.w;
    vb[4] = h2f(cb[4]) + ub1.x; vb[5] = h2f(cb[5]) + ub1.y;
    vb[6] = h2f(cb[6]) + ub1.z; vb[7] = h2f(cb[7]) + ub1.w;
    float mx = -3.4e38f;
#pragma unroll
    for (int i = 0; i < 8; ++i) mx = fmaxf(mx, fmaxf(va[i], vb[i]));
#pragma unroll
    for (int m = 1; m < 64; m <<= 1) mx = fmaxf(mx, __shfl_xor(mx, m));
    __shared__ float sM[4], sS[4];
    if (!lane) sM[wv] = mx;
    __syncthreads();
    mx = fmaxf(fmaxf(sM[0], sM[1]), fmaxf(sM[2], sM[3]));
    float sum = 0.f;
#pragma unroll
    for (int i = 0; i < 8; ++i) {
        va[i] = __expf(va[i] - mx);
        vb[i] = __expf(vb[i] - mx);
        sum += va[i] + vb[i];
    }
#pragma unroll
    for (int m = 1; m < 64; m <<= 1) sum += __shfl_xor(sum, m);
    if (!lane) sS[wv] = sum;
    __syncthreads();
    sum = sS[0] + sS[1] + sS[2] + sS[3];
    float inv = 1.0f / sum;
    u16x8v oa, ob;
#pragma unroll
    for (int i = 0; i < 8; ++i) {
        oa[i] = f2h(va[i] * inv);
        ob[i] = f2h(vb[i] * inv);
    }
    row[t] = oa; row[t + 256] = ob;
}

// -------------------------------------- split-K reduce + residual + v -----
// part: [4][512][4096] fp32 chunk-planes of (sW P^T)[o,n] for one batch.
// out[o,n] = sum_z part[z][o,n] + x[o,n] + v[o]
__global__ void __launch_bounds__(256) reduce4resid(
    const float* __restrict__ part, const float* __restrict__ xr,
    const float* __restrict__ v, float* __restrict__ out)
{
    const size_t P4 = 2097152 / 4;           // float4 per plane
    size_t g = (size_t)blockIdx.x * 256 + threadIdx.x;
    const float4* p = (const float4*)part;
    float4 a = p[g];
    float4 b1 = p[g + P4], b2 = p[g + 2 * P4], b3 = p[g + 3 * P4];
    float4 xv = ((const float4*)xr)[g];
    float vc = v[g >> 10];                   // 1024 float4 per row of 4096
    float4 o;
    o.x = a.x + b1.x + b2.x + b3.x + xv.x + vc;
    o.y = a.y + b1.y + b2.y + b3.y + xv.y + vc;
    o.z = a.z + b1.z + b2.z + b3.z + xv.z + vc;
    o.w = a.w + b1.w + b2.w + b3.w + xv.w + vc;
    ((float4*)out)[g] = o;
}

// -------------------------------------------------------------- launch ----
extern "C" void kernel_launch(void* const* d_in, const int* in_sizes, int n_in,
                              void* d_out, int out_size, void* d_ws, size_t ws_size,
                              hipStream_t stream)
{
    const float* c   = (const float*)d_in[0];
    const float* s   = (const float*)d_in[1];
    const float* x   = (const float*)d_in[2];
    const float* c_w = (const float*)d_in[3];
    const float* c_b = (const float*)d_in[4];
    const float* s_w = (const float*)d_in[5];
    const float* s_b = (const float*)d_in[6];
    const float* i_w = (const float*)d_in[7];
    const float* i_b = (const float*)d_in[8];
    const float* o_w = (const float*)d_in[9];
    const float* o_b = (const float*)d_in[10];
    float* out = (float*)d_out;
    char* ws = (char*)d_ws;

    const int B = 4, C = 512, N = 4096;
    const size_t NC = (size_t)N * C;          // 2097152
    const size_t W2 = (size_t)C * C;          // 262144
    const size_t NN = (size_t)N * N;          // 16777216

    size_t off = 0;
    auto alloc = [&](size_t bytes) { size_t o = off; off += (bytes + 255) & ~(size_t)255; return o; };

    size_t o_meanC = alloc((size_t)B * C * 4);
    size_t o_rstdC = alloc((size_t)B * C * 4);
    size_t o_meanS = alloc((size_t)B * C * 4);
    size_t o_rstdS = alloc((size_t)B * C * 4);
    size_t o_cwT = alloc(W2 * 2);
    size_t o_swT = alloc(W2 * 2);
    size_t o_iwT = alloc(W2 * 2);
    size_t o_ow  = alloc(W2 * 2);
    size_t o_G   = alloc(W2 * 2);            // G[a,l] = c_w^T s_w, f16 natural
    size_t o_W   = alloc(W2 * 2);            // W = o_w @ i_w, f16 natural
    size_t o_v   = alloc((size_t)C * 4);     // v = o_w@i_b + o_b
    size_t o_wu  = alloc((size_t)C * 4);     // wu = s_w^T c_b
    size_t o_u   = alloc((size_t)B * N * 4); // u[b,m]
    size_t o_cnT = alloc(B * NC * 2);        // normalized c, transposed [B,N,C]
    size_t o_snT = alloc(B * NC * 2);        // normalized s, transposed
    size_t o_sRT = alloc(B * NC * 2);        // raw s, transposed
    size_t o_sgT = alloc(B * NC * 2);        // sgT[m,a] = (G @ sn)^T
    size_t o_sW  = alloc(B * NC * 2);        // sW[o,m] = W @ sR
    size_t o_P   = alloc(NN * 2);            // per-batch logits/P f16 (33.5MB)
    size_t o_pt  = alloc(4 * NC * 4);        // per-batch split-K4 partials fp32

    if (ws_size < off) { // not enough scratch: bail (will fail check loudly)
        hipMemsetAsync(d_out, 0, (size_t)out_size * 4, stream);
        return;
    }

    float* meanC = (float*)(ws + o_meanC);
    float* rstdC = (float*)(ws + o_rstdC);
    float* meanS = (float*)(ws + o_meanS);
    float* rstdS = (float*)(ws + o_rstdS);
    u16* cwT = (u16*)(ws + o_cwT);
    u16* swT = (u16*)(ws + o_swT);
    u16* iwT = (u16*)(ws + o_iwT);
    u16* ow  = (u16*)(ws + o_ow);
    u16* Gf  = (u16*)(ws + o_G);
    u16* Wf  = (u16*)(ws + o_W);
    float* vb = (float*)(ws + o_v);
    float* wu = (float*)(ws + o_wu);
    float* ub = (float*)(ws + o_u);
    u16* cnT = (u16*)(ws + o_cnT);
    u16* snT = (u16*)(ws + o_snT);
    u16* sRT = (u16*)(ws + o_sRT);
    u16* sgT = (u16*)(ws + o_sgT);
    u16* sW  = (u16*)(ws + o_sW);
    u16* Pb  = (u16*)(ws + o_P);
    float* part = (float*)(ws + o_pt);

    // 1) instance-norm stats
    stats_kernel<<<dim3(B * C, 2), 256, 0, stream>>>(c, s, meanC, rstdC, meanS, rstdS);
    // 2) packs: c -> cnT (norm,T); s -> snT (norm,T) + sRT (raw,T)
    pack_kernel<0><<<dim3(N / 32, C / 32, B), dim3(32, 8), 0, stream>>>(c, meanC, rstdC, cnT, nullptr);
    pack_kernel<2><<<dim3(N / 32, C / 32, B), dim3(32, 8), 0, stream>>>(s, meanS, rstdS, snT, sRT);
    // 3) weight preps
    tpack512<<<dim3(16, 16), dim3(32, 8), 0, stream>>>(c_w, cwT);
    tpack512<<<dim3(16, 16), dim3(32, 8), 0, stream>>>(s_w, swT);
    tpack512<<<dim3(16, 16), dim3(32, 8), 0, stream>>>(i_w, iwT);
    split_f16<<<dim3((int)(W2 / 256)), 256, 0, stream>>>(o_w, ow, (int)W2);
    vbias_kernel<<<dim3(2), 256, 0, stream>>>(o_w, i_b, o_b, vb);
    wu_kernel<<<dim3(2), 256, 0, stream>>>(s_w, c_b, wu);
    // G[a,l] = sum_k c_w[k,a]*s_w[k,l]   (natural [a,l])
    gemm_bt<EPI_PLAIN_F16><<<dim3(4, 4, 1), 256, 0, stream>>>(
        cwT, swT, 512, 512, nullptr, nullptr, Gf, 512, 1, 0, 0, 0, 0, 0);
    // W[o,c] = sum_k o_w[o,k]*i_w[k,c]   (natural [o,c])
    gemm_bt<EPI_PLAIN_F16><<<dim3(4, 4, 1), 256, 0, stream>>>(
        ow, iwT, 512, 512, nullptr, nullptr, Wf, 512, 1, 0, 0, 0, 0, 0);
    // 4) sgT[m,a] = sum_l snT[m,l]*G[a,l]  — A=snT (big), B=G (tiny),
    //    output natural [m,a], coalesced.  grid: x=4 a-tiles, y=32 m-tiles.
    gemm_bt<EPI_PLAIN_F16><<<dim3(4, 32, B), 256, 0, stream>>>(
        snT, Gf, 512, 512, nullptr, nullptr, sgT, 512, 1,
        (long)NC, 0, 0, 0, (long)NC);
    // 5) sW[o,m] = sum_c W[o,c]*sRT[m,c]  — output natural [o,m], coalesced.
    gemm_bt<EPI_PLAIN_F16><<<dim3(32, 4, B), 256, 0, stream>>>(
        Wf, sRT, 512, 512, nullptr, nullptr, sW, 4096, 1,
        0, 0, (long)NC, 0, (long)NC);
    // 6) u[b,m] = sum_l snT[b,m,l]*wu[l]
    rowdot_kernel<<<dim3(B * N / 4), 256, 0, stream>>>(snT, wu, ub);
    // 7) per-batch attention (P stays cache-resident); PV writes the final
    //    output via reduce4resid (+x +v) — no final conv.
    for (int b = 0; b < B; ++b) {
        // logits L[n,m] = sum_a cnT[n,a]*sgT[m,a] -> Pb f16
        gemm_bt<EPI_PLAIN_F16><<<dim3(32, 32, 1), 256, 0, stream>>>(
            cnT + (size_t)b * NC, sgT + (size_t)b * NC,
            512, 512, nullptr, nullptr, Pb, 4096, 1, 0, 0, 0, 0, 0);
        // P = softmax_m(L + u[m]) in place
        softmax16<<<dim3(N), 256, 0, stream>>>(Pb, ub + (size_t)b * N);
        // out_pre[o,n] = sum_m sW[o,m]*P[n,m], split-K4 fp32 partials
        gemm_bt<EPI_F32><<<dim3(32, 4, 4), 256, 0, stream>>>(
            sW + (size_t)b * NC, Pb, 1024, 4096, nullptr,
            part, nullptr, 4096, 4,
            0, 1024L, 0, 1024L, (long)NC);
        // out = sum partials + x + v   (coalesced float4)
        reduce4resid<<<dim3((int)(NC / 1024)), 256, 0, stream>>>(
            part, x + (size_t)b * NC, vb, out + (size_t)b * NC);
    }
}

// Round 9
// 371.815 us; speedup vs baseline: 1.3514x; 1.1963x over previous
//
#include <hip/hip_runtime.h>

typedef unsigned short u16;
typedef _Float16 f16x8 __attribute__((ext_vector_type(8)));
typedef float f32x4 __attribute__((ext_vector_type(4)));
typedef u16 u16x4 __attribute__((ext_vector_type(4)));
typedef u16 u16x8v __attribute__((ext_vector_type(8)));

__device__ __forceinline__ u16 f2h(float f) {
    _Float16 h = (_Float16)f;
    return __builtin_bit_cast(u16, h);
}
__device__ __forceinline__ float h2f(u16 u) {
    return (float)__builtin_bit_cast(_Float16, u);
}

// ---------------------------------------------------------------- stats ----
__global__ void __launch_bounds__(256) stats_kernel(
    const float* __restrict__ c, const float* __restrict__ s,
    float* __restrict__ mC, float* __restrict__ rC,
    float* __restrict__ mS, float* __restrict__ rS)
{
    const float* src = (blockIdx.y ? s : c) + (size_t)blockIdx.x * 4096;
    int t = threadIdx.x, lane = t & 63, wv = t >> 6;
    const float4* p = (const float4*)src;
    float sum = 0.f, sq = 0.f;
#pragma unroll
    for (int i = 0; i < 4; ++i) {
        float4 v = p[t + 256 * i];
        sum += v.x + v.y + v.z + v.w;
        sq  += v.x * v.x + v.y * v.y + v.z * v.z + v.w * v.w;
    }
#pragma unroll
    for (int m = 1; m < 64; m <<= 1) {
        sum += __shfl_xor(sum, m);
        sq  += __shfl_xor(sq, m);
    }
    __shared__ float sa[4], sb[4];
    if (!lane) { sa[wv] = sum; sb[wv] = sq; }
    __syncthreads();
    if (t == 0) {
        float S = sa[0] + sa[1] + sa[2] + sa[3];
        float Q = sb[0] + sb[1] + sb[2] + sb[3];
        float mean = S * (1.0f / 4096.0f);
        float var = (Q - 4096.0f * mean * mean) * (1.0f / 4095.0f);
        float rstd = rsqrtf(var + 1e-5f);
        if (blockIdx.y) { mS[blockIdx.x] = mean; rS[blockIdx.x] = rstd; }
        else            { mC[blockIdx.x] = mean; rC[blockIdx.x] = rstd; }
    }
}

// ------------------------------------------------- fused transpose pack ----
// z 0..3: batch z of c -> cnT (normalized, transposed [B,N,C])
// z 4..7: batch z-4 of s -> snT (normalized,T) + sRT (raw,T)
__global__ void __launch_bounds__(256) packall(
    const float* __restrict__ c, const float* __restrict__ s,
    const float* __restrict__ mC, const float* __restrict__ rC,
    const float* __restrict__ mS, const float* __restrict__ rS,
    u16* __restrict__ cnT, u16* __restrict__ snT, u16* __restrict__ sRT)
{
    __shared__ float tile[32][33];
    int z = blockIdx.z;
    bool isS = z >= 4;
    int b = isS ? z - 4 : z;
    const float* src  = isS ? s : c;
    const float* mean = isS ? mS : mC;
    const float* rstd = isS ? rS : rC;
    u16* dh = isS ? snT : cnT;
    int n0 = blockIdx.x * 32, c0 = blockIdx.y * 32;
    int tx = threadIdx.x, ty = threadIdx.y;
    const float* sbp = src + ((size_t)b * 512 + c0) * 4096 + n0;
#pragma unroll
    for (int it = 0; it < 4; ++it) {
        int cc = ty + it * 8;
        tile[cc][tx] = sbp[(size_t)cc * 4096 + tx];
    }
    __syncthreads();
    int ch = c0 + tx;
    float mn = mean[b * 512 + ch];
    float rs = rstd[b * 512 + ch];
    size_t obase = ((size_t)b * 4096 + n0) * 512 + c0;
#pragma unroll
    for (int it = 0; it < 4; ++it) {
        int r = ty + it * 8;
        float v = tile[tx][r];
        size_t o = obase + (size_t)r * 512 + tx;
        dh[o] = f2h((v - mn) * rs);
        if (isS) sRT[o] = f2h(v);
    }
}

// ------------------------------------------------- fused weight prep ------
// z 0..2: transpose-pack c_w/s_w/i_w -> cwT/swT/iwT (f16)
// z == 3: straight f16 cast o_w -> ow
__global__ void __launch_bounds__(256) prep_kernel(
    const float* __restrict__ c_w, const float* __restrict__ s_w,
    const float* __restrict__ i_w, const float* __restrict__ o_w,
    u16* __restrict__ cwT, u16* __restrict__ swT,
    u16* __restrict__ iwT, u16* __restrict__ ow)
{
    int z = blockIdx.z;
    int tx = threadIdx.x, ty = threadIdx.y;
    if (z == 3) {
        size_t base = ((size_t)(blockIdx.y * 16 + blockIdx.x) * 256 +
                       (ty * 32 + tx)) * 4;
        float4 v = *(const float4*)(o_w + base);
        u16x4 o;
        o[0] = f2h(v.x); o[1] = f2h(v.y); o[2] = f2h(v.z); o[3] = f2h(v.w);
        *(u16x4*)(ow + base) = o;
        return;
    }
    const float* w = (z == 0) ? c_w : (z == 1) ? s_w : i_w;
    u16* wT = (z == 0) ? cwT : (z == 1) ? swT : iwT;
    __shared__ float tile[32][33];
    int c0 = blockIdx.x * 32, k0 = blockIdx.y * 32;
#pragma unroll
    for (int it = 0; it < 4; ++it) {
        int kk = ty + it * 8;
        tile[kk][tx] = w[(size_t)(k0 + kk) * 512 + c0 + tx];
    }
    __syncthreads();
#pragma unroll
    for (int it = 0; it < 4; ++it) {
        int r = ty + it * 8;
        wT[(size_t)(c0 + r) * 512 + k0 + tx] = f2h(tile[tx][r]);
    }
}

// ------------------------------------------------- fused bias prep --------
// blocks 0,1: v[o] = o_b[o] + sum_k o_w[o,k] i_b[k]
// blocks 2,3: wu[l] = sum_k c_b[k] s_w[k,l]
__global__ void __launch_bounds__(256) bias_prep(
    const float* __restrict__ o_w, const float* __restrict__ i_b,
    const float* __restrict__ o_b, const float* __restrict__ s_w,
    const float* __restrict__ c_b, float* __restrict__ v,
    float* __restrict__ wu)
{
    __shared__ float buf[512];
    int t = threadIdx.x;
    bool isWu = blockIdx.x >= 2;
    const float* vec = isWu ? c_b : i_b;
    buf[t] = vec[t]; buf[t + 256] = vec[t + 256];
    __syncthreads();
    int o = (blockIdx.x & 1) * 256 + t;
    if (!isWu) {
        float acc = o_b[o];
        const float* row = o_w + (size_t)o * 512;
        for (int k = 0; k < 512; ++k) acc += row[k] * buf[k];
        v[o] = acc;
    } else {
        float acc = 0.f;
        for (int k = 0; k < 512; ++k) acc += buf[k] * s_w[(size_t)k * 512 + o];
        wu[o] = acc;
    }
}

// u[r] = sum_l snT[r,l] * wu[l]   (r over B*4096 rows; 1 wave per row)
__global__ void __launch_bounds__(256) rowdot_kernel(
    const u16* __restrict__ snT, const float* __restrict__ wu,
    float* __restrict__ u)
{
    __shared__ float swu[512];
    int t = threadIdx.x;
    swu[t] = wu[t]; swu[t + 256] = wu[t + 256];
    __syncthreads();
    int lane = t & 63, wv = t >> 6;
    int row = blockIdx.x * 4 + wv;
    u16x8v h = *(const u16x8v*)(snT + (size_t)row * 512 + lane * 8);
    float acc = 0.f;
#pragma unroll
    for (int i = 0; i < 8; ++i) acc += h2f(h[i]) * swu[lane * 8 + i];
#pragma unroll
    for (int m = 1; m < 64; m <<= 1) acc += __shfl_xor(acc, m);
    if (!lane) u[row] = acc;
}

// ---------------------------------------------------------------- GEMM ----
// C[i,j] = sum_k A[i,k]*B[j,k]  (A:[M,ldk] rowmajor, B:[N,ldk] rowmajor),
// K steps of the k loop. z decomposes as batch = z/zdiv, chunk = z%zdiv:
//   A += batch*aBatch + chunk*aChunk;  B += batch*bBatch + chunk*bChunk;
//   out += z*oZ.   bias nullable.
#define EPI_F32       0
#define EPI_PLAIN_F16 2

__device__ __forceinline__ void stage_tile(
    const u16* __restrict__ g, int ldk, int i0, int k0, char* tile, int wv, int lane)
{
#pragma unroll
    for (int cc = 0; cc < 4; ++cc) {
        int chunk = (wv * 4 + cc) * 64 + lane;   // 16B-chunk linear index in tile
        int row  = chunk >> 3;                   // 8 chunks (128B) per row
        int slot = chunk & 7;
        int gc   = slot ^ (row & 7);             // pre-swizzled source column-chunk
        const u16* gp = g + (size_t)(i0 + row) * ldk + (k0 + gc * 8);
        char* lp = tile + (size_t)(wv * 4 + cc) * 1024; // wave-uniform base
        __builtin_amdgcn_global_load_lds(
            (const __attribute__((address_space(1))) unsigned int*)gp,
            (__attribute__((address_space(3))) unsigned int*)lp, 16, 0, 0);
    }
}

template<int EPI>
__global__ void __launch_bounds__(256) gemm_bt(
    const u16* __restrict__ A_, const u16* __restrict__ B_,
    int K, int ldk, const float* __restrict__ bias,
    float* __restrict__ outF_, u16* __restrict__ outH_,
    int ldo, int zdiv,
    long aBatch, long aChunk, long bBatch, long bChunk, long oZ)
{
    __shared__ char smem[32768];
    char* sA = smem;
    char* sB = smem + 16384;

    int bz = blockIdx.z;
    int batch = bz / zdiv, chunk = bz % zdiv;
    const u16* A  = A_ + (size_t)batch * aBatch + (size_t)chunk * aChunk;
    const u16* Bm = B_ + (size_t)batch * bBatch + (size_t)chunk * bChunk;

    int i0 = blockIdx.y * 128, j0 = blockIdx.x * 128;
    int tid = threadIdx.x, lane = tid & 63, wv = tid >> 6;
    int wr = wv >> 1, wc = wv & 1;
    int r15 = lane & 15, h4 = lane >> 4;

    f32x4 zero = {0.f, 0.f, 0.f, 0.f};
    f32x4 acc[4][4];
#pragma unroll
    for (int m = 0; m < 4; ++m)
#pragma unroll
        for (int n = 0; n < 4; ++n) acc[m][n] = zero;

    for (int k0 = 0; k0 < K; k0 += 64) {
        stage_tile(A, ldk, i0, k0, sA, wv, lane);
        stage_tile(Bm, ldk, j0, k0, sB, wv, lane);
        asm volatile("s_waitcnt vmcnt(0)" ::: "memory");
        __syncthreads();
#pragma unroll
        for (int ks = 0; ks < 2; ++ks) {
            f16x8 a[4], b[4];
#pragma unroll
            for (int m = 0; m < 4; ++m) {
                int row = wr * 64 + m * 16 + r15;
                int off = row * 128 + (((ks * 4 + h4) ^ (row & 7)) << 4);
                a[m] = *(const f16x8*)(sA + off);
            }
#pragma unroll
            for (int n = 0; n < 4; ++n) {
                int col = wc * 64 + n * 16 + r15;
                int off = col * 128 + (((ks * 4 + h4) ^ (col & 7)) << 4);
                b[n] = *(const f16x8*)(sB + off);
            }
#pragma unroll
            for (int m = 0; m < 4; ++m)
#pragma unroll
                for (int n = 0; n < 4; ++n)
                    acc[m][n] = __builtin_amdgcn_mfma_f32_16x16x32_f16(a[m], b[n], acc[m][n], 0, 0, 0);
        }
        __syncthreads();
    }

    float* outF = outF_ ? outF_ + (size_t)bz * oZ : nullptr;
    u16* outH = outH_ ? outH_ + (size_t)bz * oZ : nullptr;

#pragma unroll
    for (int m = 0; m < 4; ++m)
#pragma unroll
        for (int n = 0; n < 4; ++n) {
            int ibase = i0 + wr * 64 + m * 16 + h4 * 4;
            int j = j0 + wc * 64 + n * 16 + r15;
#pragma unroll
            for (int r = 0; r < 4; ++r) {
                int i = ibase + r;
                float v = acc[m][n][r];
                if constexpr (EPI == EPI_PLAIN_F16) {
                    if (bias) v += bias[i];
                    outH[(size_t)i * ldo + j] = f2h(v);
                } else { // EPI_F32
                    outF[(size_t)i * ldo + j] = v;
                }
            }
        }
}

// ------------------------------------------------------ softmax (f16) ----
// pair dispatch: row = blockIdx.x over 2*4096; u base per pair, per-batch
// offset derived from row>>12. L row f16 += u[col], softmax over m, IN PLACE.
__global__ void __launch_bounds__(256) softmax16(
    u16* __restrict__ LP, const float* __restrict__ u)
{
    u16x8v* row = (u16x8v*)(LP + (size_t)blockIdx.x * 4096);
    const float4* u4 = (const float4*)(u + (size_t)(blockIdx.x >> 12) * 4096);
    int t = threadIdx.x, lane = t & 63, wv = t >> 6;
    u16x8v ca = row[t], cb = row[t + 256];
    float4 ua0 = u4[2 * t], ua1 = u4[2 * t + 1];
    float4 ub0 = u4[2 * (t + 256)], ub1 = u4[2 * (t + 256) + 1];
    float va[8], vb[8];
    va[0] = h2f(ca[0]) + ua0.x; va[1] = h2f(ca[1]) + ua0.y;
    va[2] = h2f(ca[2]) + ua0.z; va[3] = h2f(ca[3]) + ua0.w;
    va[4] = h2f(ca[4]) + ua1.x; va[5] = h2f(ca[5]) + ua1.y;
    va[6] = h2f(ca[6]) + ua1.z; va[7] = h2f(ca[7]) + ua1.w;
    vb[0] = h2f(cb[0]) + ub0.x; vb[1] = h2f(cb[1]) + ub0.y;
    vb[2] = h2f(cb[2]) + ub0.z; vb[3] = h2f(cb[3]) + ub0.w;
    vb[4] = h2f(cb[4]) + ub1.x; vb[5] = h2f(cb[5]) + ub1.y;
    vb[6] = h2f(cb[6]) + ub1.z; vb[7] = h2f(cb[7]) + ub1.w;
    float mx = -3.4e38f;
#pragma unroll
    for (int i = 0; i < 8; ++i) mx = fmaxf(mx, fmaxf(va[i], vb[i]));
#pragma unroll
    for (int m = 1; m < 64; m <<= 1) mx = fmaxf(mx, __shfl_xor(mx, m));
    __shared__ float sM[4], sS[4];
    if (!lane) sM[wv] = mx;
    __syncthreads();
    mx = fmaxf(fmaxf(sM[0], sM[1]), fmaxf(sM[2], sM[3]));
    float sum = 0.f;
#pragma unroll
    for (int i = 0; i < 8; ++i) {
        va[i] = __expf(va[i] - mx);
        vb[i] = __expf(vb[i] - mx);
        sum += va[i] + vb[i];
    }
#pragma unroll
    for (int m = 1; m < 64; m <<= 1) sum += __shfl_xor(sum, m);
    if (!lane) sS[wv] = sum;
    __syncthreads();
    sum = sS[0] + sS[1] + sS[2] + sS[3];
    float inv = 1.0f / sum;
    u16x8v oa, ob;
#pragma unroll
    for (int i = 0; i < 8; ++i) {
        oa[i] = f2h(va[i] * inv);
        ob[i] = f2h(vb[i] * inv);
    }
    row[t] = oa; row[t + 256] = ob;
}

// -------------------------------------- split-K reduce + residual + v -----
// part: [2][4][512][4096] f16 chunk-planes of (sW P^T)[o,n] for a batch pair.
// blockIdx.y = pair-local batch. out[o,n] = sum_k part + x[o,n] + v[o]
__global__ void __launch_bounds__(256) reduce4resid(
    const u16* __restrict__ part, const float* __restrict__ xr,
    const float* __restrict__ v, float* __restrict__ out)
{
    const size_t PLANE = 2097152;
    int b = blockIdx.y;
    size_t g8 = ((size_t)blockIdx.x * 256 + threadIdx.x) * 8;
    const u16* p0 = part + (size_t)b * 4 * PLANE + g8;
    float acc[8] = {0.f, 0.f, 0.f, 0.f, 0.f, 0.f, 0.f, 0.f};
#pragma unroll
    for (int k = 0; k < 4; ++k) {
        u16x8v h = *(const u16x8v*)(p0 + (size_t)k * PLANE);
#pragma unroll
        for (int i = 0; i < 8; ++i) acc[i] += h2f(h[i]);
    }
    const float4* xv = (const float4*)(xr + (size_t)b * PLANE + g8);
    float4 x0 = xv[0], x1 = xv[1];
    float vc = v[g8 >> 12];
    float4 o0, o1;
    o0.x = acc[0] + x0.x + vc; o0.y = acc[1] + x0.y + vc;
    o0.z = acc[2] + x0.z + vc; o0.w = acc[3] + x0.w + vc;
    o1.x = acc[4] + x1.x + vc; o1.y = acc[5] + x1.y + vc;
    o1.z = acc[6] + x1.z + vc; o1.w = acc[7] + x1.w + vc;
    float4* op = (float4*)(out + (size_t)b * PLANE + g8);
    op[0] = o0; op[1] = o1;
}

// -------------------------------------------------------------- launch ----
extern "C" void kernel_launch(void* const* d_in, const int* in_sizes, int n_in,
                              void* d_out, int out_size, void* d_ws, size_t ws_size,
                              hipStream_t stream)
{
    const float* c   = (const float*)d_in[0];
    const float* s   = (const float*)d_in[1];
    const float* x   = (const float*)d_in[2];
    const float* c_w = (const float*)d_in[3];
    const float* c_b = (const float*)d_in[4];
    const float* s_w = (const float*)d_in[5];
    const float* s_b = (const float*)d_in[6];
    const float* i_w = (const float*)d_in[7];
    const float* i_b = (const float*)d_in[8];
    const float* o_w = (const float*)d_in[9];
    const float* o_b = (const float*)d_in[10];
    float* out = (float*)d_out;
    char* ws = (char*)d_ws;

    const int B = 4, C = 512, N = 4096;
    const size_t NC = (size_t)N * C;          // 2097152
    const size_t W2 = (size_t)C * C;          // 262144
    const size_t NN = (size_t)N * N;          // 16777216

    size_t off = 0;
    auto alloc = [&](size_t bytes) { size_t o = off; off += (bytes + 255) & ~(size_t)255; return o; };

    size_t o_meanC = alloc((size_t)B * C * 4);
    size_t o_rstdC = alloc((size_t)B * C * 4);
    size_t o_meanS = alloc((size_t)B * C * 4);
    size_t o_rstdS = alloc((size_t)B * C * 4);
    // NOTE: cwT..W contiguous W2*2-byte blocks (offset-trick batching relies on it)
    size_t o_cwT = alloc(W2 * 2);
    size_t o_swT = alloc(W2 * 2);
    size_t o_iwT = alloc(W2 * 2);
    size_t o_ow  = alloc(W2 * 2);
    size_t o_G   = alloc(W2 * 2);            // G[a,l] = c_w^T s_w, f16 natural
    size_t o_W   = alloc(W2 * 2);            // W = o_w @ i_w, f16 natural
    size_t o_v   = alloc((size_t)C * 4);     // v = o_w@i_b + o_b
    size_t o_wu  = alloc((size_t)C * 4);     // wu = s_w^T c_b
    size_t o_u   = alloc((size_t)B * N * 4); // u[b,m]
    size_t o_cnT = alloc(B * NC * 2);        // normalized c, transposed [B,N,C]
    size_t o_snT = alloc(B * NC * 2);        // normalized s, transposed
    size_t o_sRT = alloc(B * NC * 2);        // raw s, transposed
    size_t o_sgT = alloc(B * NC * 2);        // sgT[m,a] = (G @ sn)^T
    size_t o_sW  = alloc(B * NC * 2);        // sW[o,m] = W @ sR
    size_t o_P   = alloc(2 * NN * 2);        // PAIR logits/P f16 (67MB)
    size_t o_pt  = alloc(8 * NC * 2);        // pair split-K4 partials f16 (33.5MB)

    if (ws_size < off) { // not enough scratch: bail (will fail check loudly)
        hipMemsetAsync(d_out, 0, (size_t)out_size * 4, stream);
        return;
    }

    float* meanC = (float*)(ws + o_meanC);
    float* rstdC = (float*)(ws + o_rstdC);
    float* meanS = (float*)(ws + o_meanS);
    float* rstdS = (float*)(ws + o_rstdS);
    u16* cwT = (u16*)(ws + o_cwT);
    u16* swT = (u16*)(ws + o_swT);
    u16* iwT = (u16*)(ws + o_iwT);
    u16* ow  = (u16*)(ws + o_ow);
    u16* Gf  = (u16*)(ws + o_G);
    u16* Wf  = (u16*)(ws + o_W);
    float* vb = (float*)(ws + o_v);
    float* wu = (float*)(ws + o_wu);
    float* ub = (float*)(ws + o_u);
    u16* cnT = (u16*)(ws + o_cnT);
    u16* snT = (u16*)(ws + o_snT);
    u16* sRT = (u16*)(ws + o_sRT);
    u16* sgT = (u16*)(ws + o_sgT);
    u16* sW  = (u16*)(ws + o_sW);
    u16* Pb  = (u16*)(ws + o_P);
    u16* partH = (u16*)(ws + o_pt);

    // 1) instance-norm stats
    stats_kernel<<<dim3(B * C, 2), 256, 0, stream>>>(c, s, meanC, rstdC, meanS, rstdS);
    // 2) fused packs (c and s in one dispatch, 1024 blocks)
    packall<<<dim3(N / 32, C / 32, 8), dim3(32, 8), 0, stream>>>(
        c, s, meanC, rstdC, meanS, rstdS, cnT, snT, sRT);
    // 3) fused weight preps
    prep_kernel<<<dim3(16, 16, 4), dim3(32, 8), 0, stream>>>(
        c_w, s_w, i_w, o_w, cwT, swT, iwT, ow);
    bias_prep<<<dim3(4), 256, 0, stream>>>(o_w, i_b, o_b, s_w, c_b, vb, wu);
    // G[a,l] = c_w^T s_w  and  W[o,c] = o_w i_w  in ONE dispatch:
    // z=1 offsets A by 3*W2 (cwT->ow), B by W2 (swT->iwT), out by W2 (G->W).
    gemm_bt<EPI_PLAIN_F16><<<dim3(4, 4, 2), 256, 0, stream>>>(
        cwT, swT, 512, 512, nullptr, nullptr, Gf, 512, 1,
        (long)(3 * W2), 0, (long)W2, 0, (long)W2);
    // 4) sgT[m,a] = sum_l snT[m,l]*G[a,l]  (natural [m,a], coalesced)
    gemm_bt<EPI_PLAIN_F16><<<dim3(4, 32, B), 256, 0, stream>>>(
        snT, Gf, 512, 512, nullptr, nullptr, sgT, 512, 1,
        (long)NC, 0, 0, 0, (long)NC);
    // 5) sW[o,m] = sum_c W[o,c]*sRT[m,c]  (natural [o,m], coalesced)
    gemm_bt<EPI_PLAIN_F16><<<dim3(32, 4, B), 256, 0, stream>>>(
        Wf, sRT, 512, 512, nullptr, nullptr, sW, 4096, 1,
        0, 0, (long)NC, 0, (long)NC);
    // 6) u[b,m] = sum_l snT[b,m,l]*wu[l]
    rowdot_kernel<<<dim3(B * N / 4), 256, 0, stream>>>(snT, wu, ub);
    // 7) attention in batch PAIRS (P pair stays L3-resident)
    for (int pb0 = 0; pb0 < B; pb0 += 2) {
        // logits: L[z,n,m] = sum_a cnT[n,a]*sgT[m,a], 2048 blocks
        gemm_bt<EPI_PLAIN_F16><<<dim3(32, 32, 2), 256, 0, stream>>>(
            cnT + (size_t)pb0 * NC, sgT + (size_t)pb0 * NC,
            512, 512, nullptr, nullptr, Pb, 4096, 1,
            (long)NC, 0, (long)NC, 0, (long)NN);
        // P = softmax_m(L + u[m]) in place, 8192 rows
        softmax16<<<dim3(2 * N), 256, 0, stream>>>(Pb, ub + (size_t)pb0 * N);
        // out_pre[o,n] = sum_m sW[o,m]*P[n,m]; split-K4 per batch, pair in
        // one 1024-block dispatch; f16 partials [b][chunk][o][n].
        gemm_bt<EPI_PLAIN_F16><<<dim3(32, 4, 8), 256, 0, stream>>>(
            sW + (size_t)pb0 * NC, Pb, 1024, 4096, nullptr,
            nullptr, partH, 4096, 4,
            (long)NC, 1024L, (long)NN, 1024L, (long)NC);
        // out = sum partials + x + v   (pair, coalesced)
        reduce4resid<<<dim3((int)(NC / 2048), 2), 256, 0, stream>>>(
            partH, x + (size_t)pb0 * NC, vb, out + (size_t)pb0 * NC);
    }
}

// Round 11
// 358.268 us; speedup vs baseline: 1.4025x; 1.0378x over previous
//
#include <hip/hip_runtime.h>

typedef unsigned short u16;
typedef _Float16 f16x8 __attribute__((ext_vector_type(8)));
typedef float f32x4 __attribute__((ext_vector_type(4)));
typedef u16 u16x4 __attribute__((ext_vector_type(4)));
typedef u16 u16x8v __attribute__((ext_vector_type(8)));

__device__ __forceinline__ u16 f2h(float f) {
    _Float16 h = (_Float16)f;
    return __builtin_bit_cast(u16, h);
}
__device__ __forceinline__ float h2f(u16 u) {
    return (float)__builtin_bit_cast(_Float16, u);
}

// ---------------------------------------------------------------- stats ----
__global__ void __launch_bounds__(256) stats_kernel(
    const float* __restrict__ c, const float* __restrict__ s,
    float* __restrict__ mC, float* __restrict__ rC,
    float* __restrict__ mS, float* __restrict__ rS)
{
    const float* src = (blockIdx.y ? s : c) + (size_t)blockIdx.x * 4096;
    int t = threadIdx.x, lane = t & 63, wv = t >> 6;
    const float4* p = (const float4*)src;
    float sum = 0.f, sq = 0.f;
#pragma unroll
    for (int i = 0; i < 4; ++i) {
        float4 v = p[t + 256 * i];
        sum += v.x + v.y + v.z + v.w;
        sq  += v.x * v.x + v.y * v.y + v.z * v.z + v.w * v.w;
    }
#pragma unroll
    for (int m = 1; m < 64; m <<= 1) {
        sum += __shfl_xor(sum, m);
        sq  += __shfl_xor(sq, m);
    }
    __shared__ float sa[4], sb[4];
    if (!lane) { sa[wv] = sum; sb[wv] = sq; }
    __syncthreads();
    if (t == 0) {
        float S = sa[0] + sa[1] + sa[2] + sa[3];
        float Q = sb[0] + sb[1] + sb[2] + sb[3];
        float mean = S * (1.0f / 4096.0f);
        float var = (Q - 4096.0f * mean * mean) * (1.0f / 4095.0f);
        float rstd = rsqrtf(var + 1e-5f);
        if (blockIdx.y) { mS[blockIdx.x] = mean; rS[blockIdx.x] = rstd; }
        else            { mC[blockIdx.x] = mean; rC[blockIdx.x] = rstd; }
    }
}

// ------------------------------------------------- fused transpose pack ----
// z 0..3: batch z of c -> cnT (normalized, transposed [B,N,C])
// z 4..7: batch z-4 of s -> snT (normalized,T) + sRT (raw,T)
__global__ void __launch_bounds__(256) packall(
    const float* __restrict__ c, const float* __restrict__ s,
    const float* __restrict__ mC, const float* __restrict__ rC,
    const float* __restrict__ mS, const float* __restrict__ rS,
    u16* __restrict__ cnT, u16* __restrict__ snT, u16* __restrict__ sRT)
{
    __shared__ float tile[32][33];
    int z = blockIdx.z;
    bool isS = z >= 4;
    int b = isS ? z - 4 : z;
    const float* src  = isS ? s : c;
    const float* mean = isS ? mS : mC;
    const float* rstd = isS ? rS : rC;
    u16* dh = isS ? snT : cnT;
    int n0 = blockIdx.x * 32, c0 = blockIdx.y * 32;
    int tx = threadIdx.x, ty = threadIdx.y;
    const float* sbp = src + ((size_t)b * 512 + c0) * 4096 + n0;
#pragma unroll
    for (int it = 0; it < 4; ++it) {
        int cc = ty + it * 8;
        tile[cc][tx] = sbp[(size_t)cc * 4096 + tx];
    }
    __syncthreads();
    int ch = c0 + tx;
    float mn = mean[b * 512 + ch];
    float rs = rstd[b * 512 + ch];
    size_t obase = ((size_t)b * 4096 + n0) * 512 + c0;
#pragma unroll
    for (int it = 0; it < 4; ++it) {
        int r = ty + it * 8;
        float v = tile[tx][r];
        size_t o = obase + (size_t)r * 512 + tx;
        dh[o] = f2h((v - mn) * rs);
        if (isS) sRT[o] = f2h(v);
    }
}

// ------------------------------------------------- fused weight prep ------
// z 0..2: transpose-pack c_w/s_w/i_w -> cwT/swT/iwT (f16)
// z == 3: straight f16 cast o_w -> ow
__global__ void __launch_bounds__(256) prep_kernel(
    const float* __restrict__ c_w, const float* __restrict__ s_w,
    const float* __restrict__ i_w, const float* __restrict__ o_w,
    u16* __restrict__ cwT, u16* __restrict__ swT,
    u16* __restrict__ iwT, u16* __restrict__ ow)
{
    int z = blockIdx.z;
    int tx = threadIdx.x, ty = threadIdx.y;
    if (z == 3) {
        size_t base = ((size_t)(blockIdx.y * 16 + blockIdx.x) * 256 +
                       (ty * 32 + tx)) * 4;
        float4 v = *(const float4*)(o_w + base);
        u16x4 o;
        o[0] = f2h(v.x); o[1] = f2h(v.y); o[2] = f2h(v.z); o[3] = f2h(v.w);
        *(u16x4*)(ow + base) = o;
        return;
    }
    const float* w = (z == 0) ? c_w : (z == 1) ? s_w : i_w;
    u16* wT = (z == 0) ? cwT : (z == 1) ? swT : iwT;
    __shared__ float tile[32][33];
    int c0 = blockIdx.x * 32, k0 = blockIdx.y * 32;
#pragma unroll
    for (int it = 0; it < 4; ++it) {
        int kk = ty + it * 8;
        tile[kk][tx] = w[(size_t)(k0 + kk) * 512 + c0 + tx];
    }
    __syncthreads();
#pragma unroll
    for (int it = 0; it < 4; ++it) {
        int r = ty + it * 8;
        wT[(size_t)(c0 + r) * 512 + k0 + tx] = f2h(tile[tx][r]);
    }
}

// ------------------------------------------------- fused bias prep --------
// blocks 0,1: v[o] = o_b[o] + sum_k o_w[o,k] i_b[k]
// blocks 2,3: wu[l] = sum_k c_b[k] s_w[k,l]
__global__ void __launch_bounds__(256) bias_prep(
    const float* __restrict__ o_w, const float* __restrict__ i_b,
    const float* __restrict__ o_b, const float* __restrict__ s_w,
    const float* __restrict__ c_b, float* __restrict__ v,
    float* __restrict__ wu)
{
    __shared__ float buf[512];
    int t = threadIdx.x;
    bool isWu = blockIdx.x >= 2;
    const float* vec = isWu ? c_b : i_b;
    buf[t] = vec[t]; buf[t + 256] = vec[t + 256];
    __syncthreads();
    int o = (blockIdx.x & 1) * 256 + t;
    if (!isWu) {
        float acc = o_b[o];
        const float* row = o_w + (size_t)o * 512;
        for (int k = 0; k < 512; ++k) acc += row[k] * buf[k];
        v[o] = acc;
    } else {
        float acc = 0.f;
        for (int k = 0; k < 512; ++k) acc += buf[k] * s_w[(size_t)k * 512 + o];
        wu[o] = acc;
    }
}

// u[r] = sum_l snT[r,l] * wu[l]   (r over B*4096 rows; 1 wave per row)
__global__ void __launch_bounds__(256) rowdot_kernel(
    const u16* __restrict__ snT, const float* __restrict__ wu,
    float* __restrict__ u)
{
    __shared__ float swu[512];
    int t = threadIdx.x;
    swu[t] = wu[t]; swu[t + 256] = wu[t + 256];
    __syncthreads();
    int lane = t & 63, wv = t >> 6;
    int row = blockIdx.x * 4 + wv;
    u16x8v h = *(const u16x8v*)(snT + (size_t)row * 512 + lane * 8);
    float acc = 0.f;
#pragma unroll
    for (int i = 0; i < 8; ++i) acc += h2f(h[i]) * swu[lane * 8 + i];
#pragma unroll
    for (int m = 1; m < 64; m <<= 1) acc += __shfl_xor(acc, m);
    if (!lane) u[row] = acc;
}

// ---------------------------------------------------------------- GEMM ----
// C[i,j] = sum_k A[i,k]*B[j,k]  (A:[M,ldk] rowmajor, B:[N,ldk] rowmajor),
// K steps of the k loop. z decomposes as batch = z/zdiv, chunk = z%zdiv:
//   A += batch*aBatch + chunk*aChunk;  B += batch*bBatch + chunk*bChunk;
//   out += z*oZ.   bias nullable.
// 2-phase double-buffered: tile t+1's global_load_lds issued BEFORE
// computing tile t; vmcnt(8) (not 0) keeps the 8 new loads in flight.
#define EPI_F32       0
#define EPI_PLAIN_F16 2

__device__ __forceinline__ void stage_tile(
    const u16* __restrict__ g, int ldk, int i0, int k0, char* tile, int wv, int lane)
{
#pragma unroll
    for (int cc = 0; cc < 4; ++cc) {
        int chunk = (wv * 4 + cc) * 64 + lane;   // 16B-chunk linear index in tile
        int row  = chunk >> 3;                   // 8 chunks (128B) per row
        int slot = chunk & 7;
        int gc   = slot ^ (row & 7);             // pre-swizzled source column-chunk
        const u16* gp = g + (size_t)(i0 + row) * ldk + (k0 + gc * 8);
        char* lp = tile + (size_t)(wv * 4 + cc) * 1024; // wave-uniform base
        __builtin_amdgcn_global_load_lds(
            (const __attribute__((address_space(1))) unsigned int*)gp,
            (__attribute__((address_space(3))) unsigned int*)lp, 16, 0, 0);
    }
}

template<int EPI>
__global__ void __launch_bounds__(256) gemm_bt(
    const u16* __restrict__ A_, const u16* __restrict__ B_,
    int K, int ldk, const float* __restrict__ bias,
    float* __restrict__ outF_, u16* __restrict__ outH_,
    int ldo, int zdiv,
    long aBatch, long aChunk, long bBatch, long bChunk, long oZ)
{
    __shared__ char smem[65536];                 // [buf][A|B]: A0,B0 | A1,B1

    int bz = blockIdx.z;
    int batch = bz / zdiv, chunk = bz % zdiv;
    const u16* A  = A_ + (size_t)batch * aBatch + (size_t)chunk * aChunk;
    const u16* Bm = B_ + (size_t)batch * bBatch + (size_t)chunk * bChunk;

    int i0 = blockIdx.y * 128, j0 = blockIdx.x * 128;
    int tid = threadIdx.x, lane = tid & 63, wv = tid >> 6;
    int wr = wv >> 1, wc = wv & 1;
    int r15 = lane & 15, h4 = lane >> 4;

    f32x4 zero = {0.f, 0.f, 0.f, 0.f};
    f32x4 acc[4][4];
#pragma unroll
    for (int m = 0; m < 4; ++m)
#pragma unroll
        for (int n = 0; n < 4; ++n) acc[m][n] = zero;

    // prologue: stage tile 0 into buf 0
    stage_tile(A, ldk, i0, 0, smem, wv, lane);
    stage_tile(Bm, ldk, j0, 0, smem + 16384, wv, lane);

    int nk = K >> 6;
    for (int t = 0; t < nk; ++t) {
        int cur = t & 1;
        char* sAc = smem + cur * 32768;
        char* sBc = sAc + 16384;
        if (t + 1 < nk) {
            char* sAn = smem + (cur ^ 1) * 32768;
            // issue next tile's loads BEFORE waiting on the current tile
            stage_tile(A, ldk, i0, (t + 1) * 64, sAn, wv, lane);
            stage_tile(Bm, ldk, j0, (t + 1) * 64, sAn + 16384, wv, lane);
            // per-thread FIFO: waiting to 8 outstanding retires tile t's 8
            asm volatile("s_waitcnt vmcnt(8)" ::: "memory");
        } else {
            asm volatile("s_waitcnt vmcnt(0)" ::: "memory");
        }
        __syncthreads();
#pragma unroll
        for (int ks = 0; ks < 2; ++ks) {
            f16x8 a[4], b[4];
#pragma unroll
            for (int m = 0; m < 4; ++m) {
                int row = wr * 64 + m * 16 + r15;
                int off = row * 128 + (((ks * 4 + h4) ^ (row & 7)) << 4);
                a[m] = *(const f16x8*)(sAc + off);
            }
#pragma unroll
            for (int n = 0; n < 4; ++n) {
                int col = wc * 64 + n * 16 + r15;
                int off = col * 128 + (((ks * 4 + h4) ^ (col & 7)) << 4);
                b[n] = *(const f16x8*)(sBc + off);
            }
#pragma unroll
            for (int m = 0; m < 4; ++m)
#pragma unroll
                for (int n = 0; n < 4; ++n)
                    acc[m][n] = __builtin_amdgcn_mfma_f32_16x16x32_f16(a[m], b[n], acc[m][n], 0, 0, 0);
        }
        __syncthreads();   // all waves done reading buf[cur] before it is restaged
    }

    float* outF = outF_ ? outF_ + (size_t)bz * oZ : nullptr;
    u16* outH = outH_ ? outH_ + (size_t)bz * oZ : nullptr;

#pragma unroll
    for (int m = 0; m < 4; ++m)
#pragma unroll
        for (int n = 0; n < 4; ++n) {
            int ibase = i0 + wr * 64 + m * 16 + h4 * 4;
            int j = j0 + wc * 64 + n * 16 + r15;
#pragma unroll
            for (int r = 0; r < 4; ++r) {
                int i = ibase + r;
                float v = acc[m][n][r];
                if constexpr (EPI == EPI_PLAIN_F16) {
                    if (bias) v += bias[i];
                    outH[(size_t)i * ldo + j] = f2h(v);
                } else { // EPI_F32
                    outF[(size_t)i * ldo + j] = v;
                }
            }
        }
}

// ------------------------------------------------------ softmax (f16) ----
// pair dispatch: row = blockIdx.x over 2*4096; u base per pair, per-batch
// offset derived from row>>12. L row f16 += u[col], softmax over m, IN PLACE.
__global__ void __launch_bounds__(256) softmax16(
    u16* __restrict__ LP, const float* __restrict__ u)
{
    u16x8v* row = (u16x8v*)(LP + (size_t)blockIdx.x * 4096);
    const float4* u4 = (const float4*)(u + (size_t)(blockIdx.x >> 12) * 4096);
    int t = threadIdx.x, lane = t & 63, wv = t >> 6;
    u16x8v ca = row[t], cb = row[t + 256];
    float4 ua0 = u4[2 * t], ua1 = u4[2 * t + 1];
    float4 ub0 = u4[2 * (t + 256)], ub1 = u4[2 * (t + 256) + 1];
    float va[8], vb[8];
    va[0] = h2f(ca[0]) + ua0.x; va[1] = h2f(ca[1]) + ua0.y;
    va[2] = h2f(ca[2]) + ua0.z; va[3] = h2f(ca[3]) + ua0.w;
    va[4] = h2f(ca[4]) + ua1.x; va[5] = h2f(ca[5]) + ua1.y;
    va[6] = h2f(ca[6]) + ua1.z; va[7] = h2f(ca[7]) + ua1.w;
    vb[0] = h2f(cb[0]) + ub0.x; vb[1] = h2f(cb[1]) + ub0.y;
    vb[2] = h2f(cb[2]) + ub0.z; vb[3] = h2f(cb[3]) + ub0.w;
    vb[4] = h2f(cb[4]) + ub1.x; vb[5] = h2f(cb[5]) + ub1.y;
    vb[6] = h2f(cb[6]) + ub1.z; vb[7] = h2f(cb[7]) + ub1.w;
    float mx = -3.4e38f;
#pragma unroll
    for (int i = 0; i < 8; ++i) mx = fmaxf(mx, fmaxf(va[i], vb[i]));
#pragma unroll
    for (int m = 1; m < 64; m <<= 1) mx = fmaxf(mx, __shfl_xor(mx, m));
    __shared__ float sM[4], sS[4];
    if (!lane) sM[wv] = mx;
    __syncthreads();
    mx = fmaxf(fmaxf(sM[0], sM[1]), fmaxf(sM[2], sM[3]));
    float sum = 0.f;
#pragma unroll
    for (int i = 0; i < 8; ++i) {
        va[i] = __expf(va[i] - mx);
        vb[i] = __expf(vb[i] - mx);
        sum += va[i] + vb[i];
    }
#pragma unroll
    for (int m = 1; m < 64; m <<= 1) sum += __shfl_xor(sum, m);
    if (!lane) sS[wv] = sum;
    __syncthreads();
    sum = sS[0] + sS[1] + sS[2] + sS[3];
    float inv = 1.0f / sum;
    u16x8v oa, ob;
#pragma unroll
    for (int i = 0; i < 8; ++i) {
        oa[i] = f2h(va[i] * inv);
        ob[i] = f2h(vb[i] * inv);
    }
    row[t] = oa; row[t + 256] = ob;
}

// -------------------------------------- split-K reduce + residual + v -----
// part: [2][4][512][4096] f16 chunk-planes of (sW P^T)[o,n] for a batch pair.
// blockIdx.y = pair-local batch. out[o,n] = sum_k part + x[o,n] + v[o]
__global__ void __launch_bounds__(256) reduce4resid(
    const u16* __restrict__ part, const float* __restrict__ xr,
    const float* __restrict__ v, float* __restrict__ out)
{
    const size_t PLANE = 2097152;
    int b = blockIdx.y;
    size_t g8 = ((size_t)blockIdx.x * 256 + threadIdx.x) * 8;
    const u16* p0 = part + (size_t)b * 4 * PLANE + g8;
    float acc[8] = {0.f, 0.f, 0.f, 0.f, 0.f, 0.f, 0.f, 0.f};
#pragma unroll
    for (int k = 0; k < 4; ++k) {
        u16x8v h = *(const u16x8v*)(p0 + (size_t)k * PLANE);
#pragma unroll
        for (int i = 0; i < 8; ++i) acc[i] += h2f(h[i]);
    }
    const float4* xv = (const float4*)(xr + (size_t)b * PLANE + g8);
    float4 x0 = xv[0], x1 = xv[1];
    float vc = v[g8 >> 12];
    float4 o0, o1;
    o0.x = acc[0] + x0.x + vc; o0.y = acc[1] + x0.y + vc;
    o0.z = acc[2] + x0.z + vc; o0.w = acc[3] + x0.w + vc;
    o1.x = acc[4] + x1.x + vc; o1.y = acc[5] + x1.y + vc;
    o1.z = acc[6] + x1.z + vc; o1.w = acc[7] + x1.w + vc;
    float4* op = (float4*)(out + (size_t)b * PLANE + g8);
    op[0] = o0; op[1] = o1;
}

// -------------------------------------------------------------- launch ----
extern "C" void kernel_launch(void* const* d_in, const int* in_sizes, int n_in,
                              void* d_out, int out_size, void* d_ws, size_t ws_size,
                              hipStream_t stream)
{
    const float* c   = (const float*)d_in[0];
    const float* s   = (const float*)d_in[1];
    const float* x   = (const float*)d_in[2];
    const float* c_w = (const float*)d_in[3];
    const float* c_b = (const float*)d_in[4];
    const float* s_w = (const float*)d_in[5];
    const float* s_b = (const float*)d_in[6];
    const float* i_w = (const float*)d_in[7];
    const float* i_b = (const float*)d_in[8];
    const float* o_w = (const float*)d_in[9];
    const float* o_b = (const float*)d_in[10];
    float* out = (float*)d_out;
    char* ws = (char*)d_ws;

    const int B = 4, C = 512, N = 4096;
    const size_t NC = (size_t)N * C;          // 2097152
    const size_t W2 = (size_t)C * C;          // 262144
    const size_t NN = (size_t)N * N;          // 16777216

    size_t off = 0;
    auto alloc = [&](size_t bytes) { size_t o = off; off += (bytes + 255) & ~(size_t)255; return o; };

    size_t o_meanC = alloc((size_t)B * C * 4);
    size_t o_rstdC = alloc((size_t)B * C * 4);
    size_t o_meanS = alloc((size_t)B * C * 4);
    size_t o_rstdS = alloc((size_t)B * C * 4);
    // NOTE: cwT..W contiguous W2*2-byte blocks (offset-trick batching relies on it)
    size_t o_cwT = alloc(W2 * 2);
    size_t o_swT = alloc(W2 * 2);
    size_t o_iwT = alloc(W2 * 2);
    size_t o_ow  = alloc(W2 * 2);
    size_t o_G   = alloc(W2 * 2);            // G[a,l] = c_w^T s_w, f16 natural
    size_t o_W   = alloc(W2 * 2);            // W = o_w @ i_w, f16 natural
    size_t o_v   = alloc((size_t)C * 4);     // v = o_w@i_b + o_b
    size_t o_wu  = alloc((size_t)C * 4);     // wu = s_w^T c_b
    size_t o_u   = alloc((size_t)B * N * 4); // u[b,m]
    size_t o_cnT = alloc(B * NC * 2);        // normalized c, transposed [B,N,C]
    size_t o_snT = alloc(B * NC * 2);        // normalized s, transposed
    size_t o_sRT = alloc(B * NC * 2);        // raw s, transposed
    size_t o_sgT = alloc(B * NC * 2);        // sgT[m,a] = (G @ sn)^T
    size_t o_sW  = alloc(B * NC * 2);        // sW[o,m] = W @ sR
    size_t o_P   = alloc(2 * NN * 2);        // PAIR logits/P f16 (67MB)
    size_t o_pt  = alloc(8 * NC * 2);        // pair split-K4 partials f16 (33.5MB)

    if (ws_size < off) { // not enough scratch: bail (will fail check loudly)
        (void)hipMemsetAsync(d_out, 0, (size_t)out_size * 4, stream);
        return;
    }

    float* meanC = (float*)(ws + o_meanC);
    float* rstdC = (float*)(ws + o_rstdC);
    float* meanS = (float*)(ws + o_meanS);
    float* rstdS = (float*)(ws + o_rstdS);
    u16* cwT = (u16*)(ws + o_cwT);
    u16* swT = (u16*)(ws + o_swT);
    u16* iwT = (u16*)(ws + o_iwT);
    u16* ow  = (u16*)(ws + o_ow);
    u16* Gf  = (u16*)(ws + o_G);
    u16* Wf  = (u16*)(ws + o_W);
    float* vb = (float*)(ws + o_v);
    float* wu = (float*)(ws + o_wu);
    float* ub = (float*)(ws + o_u);
    u16* cnT = (u16*)(ws + o_cnT);
    u16* snT = (u16*)(ws + o_snT);
    u16* sRT = (u16*)(ws + o_sRT);
    u16* sgT = (u16*)(ws + o_sgT);
    u16* sW  = (u16*)(ws + o_sW);
    u16* Pb  = (u16*)(ws + o_P);
    u16* partH = (u16*)(ws + o_pt);

    // 1) instance-norm stats
    stats_kernel<<<dim3(B * C, 2), 256, 0, stream>>>(c, s, meanC, rstdC, meanS, rstdS);
    // 2) fused packs (c and s in one dispatch, 1024 blocks)
    packall<<<dim3(N / 32, C / 32, 8), dim3(32, 8), 0, stream>>>(
        c, s, meanC, rstdC, meanS, rstdS, cnT, snT, sRT);
    // 3) fused weight preps
    prep_kernel<<<dim3(16, 16, 4), dim3(32, 8), 0, stream>>>(
        c_w, s_w, i_w, o_w, cwT, swT, iwT, ow);
    bias_prep<<<dim3(4), 256, 0, stream>>>(o_w, i_b, o_b, s_w, c_b, vb, wu);
    // G[a,l] = c_w^T s_w  and  W[o,c] = o_w i_w  in ONE dispatch:
    // z=1 offsets A by 3*W2 (cwT->ow), B by W2 (swT->iwT), out by W2 (G->W).
    gemm_bt<EPI_PLAIN_F16><<<dim3(4, 4, 2), 256, 0, stream>>>(
        cwT, swT, 512, 512, nullptr, nullptr, Gf, 512, 1,
        (long)(3 * W2), 0, (long)W2, 0, (long)W2);
    // 4) sgT[m,a] = sum_l snT[m,l]*G[a,l]  (natural [m,a], coalesced)
    gemm_bt<EPI_PLAIN_F16><<<dim3(4, 32, B), 256, 0, stream>>>(
        snT, Gf, 512, 512, nullptr, nullptr, sgT, 512, 1,
        (long)NC, 0, 0, 0, (long)NC);
    // 5) sW[o,m] = sum_c W[o,c]*sRT[m,c]  (natural [o,m], coalesced)
    gemm_bt<EPI_PLAIN_F16><<<dim3(32, 4, B), 256, 0, stream>>>(
        Wf, sRT, 512, 512, nullptr, nullptr, sW, 4096, 1,
        0, 0, (long)NC, 0, (long)NC);
    // 6) u[b,m] = sum_l snT[b,m,l]*wu[l]
    rowdot_kernel<<<dim3(B * N / 4), 256, 0, stream>>>(snT, wu, ub);
    // 7) attention in batch PAIRS (P pair stays L3-resident)
    for (int pb0 = 0; pb0 < B; pb0 += 2) {
        // logits: L[z,n,m] = sum_a cnT[n,a]*sgT[m,a], 2048 blocks
        gemm_bt<EPI_PLAIN_F16><<<dim3(32, 32, 2), 256, 0, stream>>>(
            cnT + (size_t)pb0 * NC, sgT + (size_t)pb0 * NC,
            512, 512, nullptr, nullptr, Pb, 4096, 1,
            (long)NC, 0, (long)NC, 0, (long)NN);
        // P = softmax_m(L + u[m]) in place, 8192 rows
        softmax16<<<dim3(2 * N), 256, 0, stream>>>(Pb, ub + (size_t)pb0 * N);
        // out_pre[o,n] = sum_m sW[o,m]*P[n,m]; split-K4 per batch, pair in
        // one 1024-block dispatch; f16 partials [b][chunk][o][n].
        gemm_bt<EPI_PLAIN_F16><<<dim3(32, 4, 8), 256, 0, stream>>>(
            sW + (size_t)pb0 * NC, Pb, 1024, 4096, nullptr,
            nullptr, partH, 4096, 4,
            (long)NC, 1024L, (long)NN, 1024L, (long)NC);
        // out = sum partials + x + v   (pair, coalesced)
        reduce4resid<<<dim3((int)(NC / 2048), 2), 256, 0, stream>>>(
            partH, x + (size_t)pb0 * NC, vb, out + (size_t)pb0 * NC);
    }
}

// Round 12
// 350.595 us; speedup vs baseline: 1.4332x; 1.0219x over previous
//
#include <hip/hip_runtime.h>

typedef unsigned short u16;
typedef _Float16 f16x8 __attribute__((ext_vector_type(8)));
typedef float f32x4 __attribute__((ext_vector_type(4)));
typedef u16 u16x4 __attribute__((ext_vector_type(4)));
typedef u16 u16x8v __attribute__((ext_vector_type(8)));

__device__ __forceinline__ u16 f2h(float f) {
    _Float16 h = (_Float16)f;
    return __builtin_bit_cast(u16, h);
}
__device__ __forceinline__ float h2f(u16 u) {
    return (float)__builtin_bit_cast(_Float16, u);
}

// ---------------------------------------------------------------- stats ----
__global__ void __launch_bounds__(256) stats_kernel(
    const float* __restrict__ c, const float* __restrict__ s,
    float* __restrict__ mC, float* __restrict__ rC,
    float* __restrict__ mS, float* __restrict__ rS)
{
    const float* src = (blockIdx.y ? s : c) + (size_t)blockIdx.x * 4096;
    int t = threadIdx.x, lane = t & 63, wv = t >> 6;
    const float4* p = (const float4*)src;
    float sum = 0.f, sq = 0.f;
#pragma unroll
    for (int i = 0; i < 4; ++i) {
        float4 v = p[t + 256 * i];
        sum += v.x + v.y + v.z + v.w;
        sq  += v.x * v.x + v.y * v.y + v.z * v.z + v.w * v.w;
    }
#pragma unroll
    for (int m = 1; m < 64; m <<= 1) {
        sum += __shfl_xor(sum, m);
        sq  += __shfl_xor(sq, m);
    }
    __shared__ float sa[4], sb[4];
    if (!lane) { sa[wv] = sum; sb[wv] = sq; }
    __syncthreads();
    if (t == 0) {
        float S = sa[0] + sa[1] + sa[2] + sa[3];
        float Q = sb[0] + sb[1] + sb[2] + sb[3];
        float mean = S * (1.0f / 4096.0f);
        float var = (Q - 4096.0f * mean * mean) * (1.0f / 4095.0f);
        float rstd = rsqrtf(var + 1e-5f);
        if (blockIdx.y) { mS[blockIdx.x] = mean; rS[blockIdx.x] = rstd; }
        else            { mC[blockIdx.x] = mean; rC[blockIdx.x] = rstd; }
    }
}

// ------------------------------------------------- fused transpose pack ----
// z 0..3: batch z of c -> cnT (normalized, transposed [B,N,C])
// z 4..7: batch z-4 of s -> snT (normalized,T) + sRT (raw,T)
__global__ void __launch_bounds__(256) packall(
    const float* __restrict__ c, const float* __restrict__ s,
    const float* __restrict__ mC, const float* __restrict__ rC,
    const float* __restrict__ mS, const float* __restrict__ rS,
    u16* __restrict__ cnT, u16* __restrict__ snT, u16* __restrict__ sRT)
{
    __shared__ float tile[32][33];
    int z = blockIdx.z;
    bool isS = z >= 4;
    int b = isS ? z - 4 : z;
    const float* src  = isS ? s : c;
    const float* mean = isS ? mS : mC;
    const float* rstd = isS ? rS : rC;
    u16* dh = isS ? snT : cnT;
    int n0 = blockIdx.x * 32, c0 = blockIdx.y * 32;
    int tx = threadIdx.x, ty = threadIdx.y;
    const float* sbp = src + ((size_t)b * 512 + c0) * 4096 + n0;
#pragma unroll
    for (int it = 0; it < 4; ++it) {
        int cc = ty + it * 8;
        tile[cc][tx] = sbp[(size_t)cc * 4096 + tx];
    }
    __syncthreads();
    int ch = c0 + tx;
    float mn = mean[b * 512 + ch];
    float rs = rstd[b * 512 + ch];
    size_t obase = ((size_t)b * 4096 + n0) * 512 + c0;
#pragma unroll
    for (int it = 0; it < 4; ++it) {
        int r = ty + it * 8;
        float v = tile[tx][r];
        size_t o = obase + (size_t)r * 512 + tx;
        dh[o] = f2h((v - mn) * rs);
        if (isS) sRT[o] = f2h(v);
    }
}

// ------------------------------------------------- fused weight prep ------
__global__ void __launch_bounds__(256) prep_kernel(
    const float* __restrict__ c_w, const float* __restrict__ s_w,
    const float* __restrict__ i_w, const float* __restrict__ o_w,
    u16* __restrict__ cwT, u16* __restrict__ swT,
    u16* __restrict__ iwT, u16* __restrict__ ow)
{
    int z = blockIdx.z;
    int tx = threadIdx.x, ty = threadIdx.y;
    if (z == 3) {
        size_t base = ((size_t)(blockIdx.y * 16 + blockIdx.x) * 256 +
                       (ty * 32 + tx)) * 4;
        float4 v = *(const float4*)(o_w + base);
        u16x4 o;
        o[0] = f2h(v.x); o[1] = f2h(v.y); o[2] = f2h(v.z); o[3] = f2h(v.w);
        *(u16x4*)(ow + base) = o;
        return;
    }
    const float* w = (z == 0) ? c_w : (z == 1) ? s_w : i_w;
    u16* wT = (z == 0) ? cwT : (z == 1) ? swT : iwT;
    __shared__ float tile[32][33];
    int c0 = blockIdx.x * 32, k0 = blockIdx.y * 32;
#pragma unroll
    for (int it = 0; it < 4; ++it) {
        int kk = ty + it * 8;
        tile[kk][tx] = w[(size_t)(k0 + kk) * 512 + c0 + tx];
    }
    __syncthreads();
#pragma unroll
    for (int it = 0; it < 4; ++it) {
        int r = ty + it * 8;
        wT[(size_t)(c0 + r) * 512 + k0 + tx] = f2h(tile[tx][r]);
    }
}

// ------------------------------------------------- fused bias prep --------
__global__ void __launch_bounds__(256) bias_prep(
    const float* __restrict__ o_w, const float* __restrict__ i_b,
    const float* __restrict__ o_b, const float* __restrict__ s_w,
    const float* __restrict__ c_b, float* __restrict__ v,
    float* __restrict__ wu)
{
    __shared__ float buf[512];
    int t = threadIdx.x;
    bool isWu = blockIdx.x >= 2;
    const float* vec = isWu ? c_b : i_b;
    buf[t] = vec[t]; buf[t + 256] = vec[t + 256];
    __syncthreads();
    int o = (blockIdx.x & 1) * 256 + t;
    if (!isWu) {
        float acc = o_b[o];
        const float* row = o_w + (size_t)o * 512;
        for (int k = 0; k < 512; ++k) acc += row[k] * buf[k];
        v[o] = acc;
    } else {
        float acc = 0.f;
        for (int k = 0; k < 512; ++k) acc += buf[k] * s_w[(size_t)k * 512 + o];
        wu[o] = acc;
    }
}

// u[r] = sum_l snT[r,l] * wu[l]
__global__ void __launch_bounds__(256) rowdot_kernel(
    const u16* __restrict__ snT, const float* __restrict__ wu,
    float* __restrict__ u)
{
    __shared__ float swu[512];
    int t = threadIdx.x;
    swu[t] = wu[t]; swu[t + 256] = wu[t + 256];
    __syncthreads();
    int lane = t & 63, wv = t >> 6;
    int row = blockIdx.x * 4 + wv;
    u16x8v h = *(const u16x8v*)(snT + (size_t)row * 512 + lane * 8);
    float acc = 0.f;
#pragma unroll
    for (int i = 0; i < 8; ++i) acc += h2f(h[i]) * swu[lane * 8 + i];
#pragma unroll
    for (int m = 1; m < 64; m <<= 1) acc += __shfl_xor(acc, m);
    if (!lane) u[row] = acc;
}

// ---------------------------------------------------------------- GEMM ----
// 256x128 tile, 512 threads (8 waves as 4M x 2N), BK=64, single-buffer.
// C[i,j] = sum_k A[i,k]*B[j,k]. z: batch = z/zdiv, chunk = z%zdiv.
// jb (nullable): per-j fp32 bias added before f2h (EPI_PLAIN_F16 only).
#define EPI_F32       0
#define EPI_PLAIN_F16 2

__device__ __forceinline__ void stageA(
    const u16* __restrict__ g, int ldk, int i0, int k0, char* tile, int wv, int lane)
{
#pragma unroll
    for (int cc = 0; cc < 4; ++cc) {
        int chunk = (wv * 4 + cc) * 64 + lane;   // 2048 chunks = 256 rows
        int row  = chunk >> 3;
        int slot = chunk & 7;
        int gc   = slot ^ (row & 7);
        const u16* gp = g + (size_t)(i0 + row) * ldk + (k0 + gc * 8);
        char* lp = tile + (size_t)(wv * 4 + cc) * 1024;
        __builtin_amdgcn_global_load_lds(
            (const __attribute__((address_space(1))) unsigned int*)gp,
            (__attribute__((address_space(3))) unsigned int*)lp, 16, 0, 0);
    }
}
__device__ __forceinline__ void stageB(
    const u16* __restrict__ g, int ldk, int j0, int k0, char* tile, int wv, int lane)
{
#pragma unroll
    for (int cc = 0; cc < 2; ++cc) {
        int chunk = (wv * 2 + cc) * 64 + lane;   // 1024 chunks = 128 rows
        int row  = chunk >> 3;
        int slot = chunk & 7;
        int gc   = slot ^ (row & 7);
        const u16* gp = g + (size_t)(j0 + row) * ldk + (k0 + gc * 8);
        char* lp = tile + (size_t)(wv * 2 + cc) * 1024;
        __builtin_amdgcn_global_load_lds(
            (const __attribute__((address_space(1))) unsigned int*)gp,
            (__attribute__((address_space(3))) unsigned int*)lp, 16, 0, 0);
    }
}

template<int EPI>
__global__ void __launch_bounds__(512) gemm_bt(
    const u16* __restrict__ A_, const u16* __restrict__ B_,
    int K, int ldk, const float* __restrict__ bias,
    const float* __restrict__ jb, long jbZ,
    float* __restrict__ outF_, u16* __restrict__ outH_,
    int ldo, int zdiv,
    long aBatch, long aChunk, long bBatch, long bChunk, long oZ)
{
    __shared__ char smem[49152];                 // A: 32KB, B: 16KB

    int bz = blockIdx.z;
    int batch = bz / zdiv, chunk = bz % zdiv;
    const u16* A  = A_ + (size_t)batch * aBatch + (size_t)chunk * aChunk;
    const u16* Bm = B_ + (size_t)batch * bBatch + (size_t)chunk * bChunk;

    int i0 = blockIdx.y * 256, j0 = blockIdx.x * 128;
    int tid = threadIdx.x, lane = tid & 63, wv = tid >> 6;
    int wr = wv >> 1, wc = wv & 1;               // 4M x 2N waves, 64x64 each
    int r15 = lane & 15, h4 = lane >> 4;

    f32x4 zero = {0.f, 0.f, 0.f, 0.f};
    f32x4 acc[4][4];
#pragma unroll
    for (int m = 0; m < 4; ++m)
#pragma unroll
        for (int n = 0; n < 4; ++n) acc[m][n] = zero;

    for (int k0 = 0; k0 < K; k0 += 64) {
        stageA(A, ldk, i0, k0, smem, wv, lane);
        stageB(Bm, ldk, j0, k0, smem + 32768, wv, lane);
        asm volatile("s_waitcnt vmcnt(0)" ::: "memory");
        __syncthreads();
#pragma unroll
        for (int ks = 0; ks < 2; ++ks) {
            f16x8 a[4], b[4];
#pragma unroll
            for (int m = 0; m < 4; ++m) {
                int row = wr * 64 + m * 16 + r15;
                int off = row * 128 + (((ks * 4 + h4) ^ (row & 7)) << 4);
                a[m] = *(const f16x8*)(smem + off);
            }
#pragma unroll
            for (int n = 0; n < 4; ++n) {
                int col = wc * 64 + n * 16 + r15;
                int off = col * 128 + (((ks * 4 + h4) ^ (col & 7)) << 4);
                b[n] = *(const f16x8*)(smem + 32768 + off);
            }
#pragma unroll
            for (int m = 0; m < 4; ++m)
#pragma unroll
                for (int n = 0; n < 4; ++n)
                    acc[m][n] = __builtin_amdgcn_mfma_f32_16x16x32_f16(a[m], b[n], acc[m][n], 0, 0, 0);
        }
        __syncthreads();
    }

    float* outF = outF_ ? outF_ + (size_t)bz * oZ : nullptr;
    u16* outH = outH_ ? outH_ + (size_t)bz * oZ : nullptr;
    const float* jbp = jb ? jb + (size_t)bz * jbZ : nullptr;

#pragma unroll
    for (int m = 0; m < 4; ++m)
#pragma unroll
        for (int n = 0; n < 4; ++n) {
            int ibase = i0 + wr * 64 + m * 16 + h4 * 4;
            int j = j0 + wc * 64 + n * 16 + r15;
#pragma unroll
            for (int r = 0; r < 4; ++r) {
                int i = ibase + r;
                float v = acc[m][n][r];
                if constexpr (EPI == EPI_PLAIN_F16) {
                    if (bias) v += bias[i];
                    if (jbp) v += jbp[j];
                    outH[(size_t)i * ldo + j] = f2h(v);
                } else { // EPI_F32
                    outF[(size_t)i * ldo + j] = v;
                }
            }
        }
}

// ------------------------------------------------------ softmax (f16) ----
// one block per row; pure in-place softmax over m (u already in logits).
__global__ void __launch_bounds__(256) softmax16(u16* __restrict__ LP)
{
    u16x8v* row = (u16x8v*)(LP + (size_t)blockIdx.x * 4096);
    int t = threadIdx.x, lane = t & 63, wv = t >> 6;
    u16x8v ca = row[t], cb = row[t + 256];
    float va[8], vb[8];
    float mx = -3.4e38f;
#pragma unroll
    for (int i = 0; i < 8; ++i) {
        va[i] = h2f(ca[i]); vb[i] = h2f(cb[i]);
        mx = fmaxf(mx, fmaxf(va[i], vb[i]));
    }
#pragma unroll
    for (int m = 1; m < 64; m <<= 1) mx = fmaxf(mx, __shfl_xor(mx, m));
    __shared__ float sM[4], sS[4];
    if (!lane) sM[wv] = mx;
    __syncthreads();
    mx = fmaxf(fmaxf(sM[0], sM[1]), fmaxf(sM[2], sM[3]));
    float sum = 0.f;
#pragma unroll
    for (int i = 0; i < 8; ++i) {
        va[i] = __expf(va[i] - mx);
        vb[i] = __expf(vb[i] - mx);
        sum += va[i] + vb[i];
    }
#pragma unroll
    for (int m = 1; m < 64; m <<= 1) sum += __shfl_xor(sum, m);
    if (!lane) sS[wv] = sum;
    __syncthreads();
    sum = sS[0] + sS[1] + sS[2] + sS[3];
    float inv = 1.0f / sum;
    u16x8v oa, ob;
#pragma unroll
    for (int i = 0; i < 8; ++i) {
        oa[i] = f2h(va[i] * inv);
        ob[i] = f2h(vb[i] * inv);
    }
    row[t] = oa; row[t + 256] = ob;
}

// -------------------------------------- split-K reduce + residual + v -----
// part: [2][4][512][4096] f16; blockIdx.y = pair-local batch.
__global__ void __launch_bounds__(256) reduce4resid(
    const u16* __restrict__ part, const float* __restrict__ xr,
    const float* __restrict__ v, float* __restrict__ out)
{
    const size_t PLANE = 2097152;
    int b = blockIdx.y;
    size_t g8 = ((size_t)blockIdx.x * 256 + threadIdx.x) * 8;
    const u16* p0 = part + (size_t)b * 4 * PLANE + g8;
    float acc[8] = {0.f, 0.f, 0.f, 0.f, 0.f, 0.f, 0.f, 0.f};
#pragma unroll
    for (int k = 0; k < 4; ++k) {
        u16x8v h = *(const u16x8v*)(p0 + (size_t)k * PLANE);
#pragma unroll
        for (int i = 0; i < 8; ++i) acc[i] += h2f(h[i]);
    }
    const float4* xv = (const float4*)(xr + (size_t)b * PLANE + g8);
    float4 x0 = xv[0], x1 = xv[1];
    float vc = v[g8 >> 12];
    float4 o0, o1;
    o0.x = acc[0] + x0.x + vc; o0.y = acc[1] + x0.y + vc;
    o0.z = acc[2] + x0.z + vc; o0.w = acc[3] + x0.w + vc;
    o1.x = acc[4] + x1.x + vc; o1.y = acc[5] + x1.y + vc;
    o1.z = acc[6] + x1.z + vc; o1.w = acc[7] + x1.w + vc;
    float4* op = (float4*)(out + (size_t)b * PLANE + g8);
    op[0] = o0; op[1] = o1;
}

// -------------------------------------------------------------- launch ----
extern "C" void kernel_launch(void* const* d_in, const int* in_sizes, int n_in,
                              void* d_out, int out_size, void* d_ws, size_t ws_size,
                              hipStream_t stream)
{
    const float* c   = (const float*)d_in[0];
    const float* s   = (const float*)d_in[1];
    const float* x   = (const float*)d_in[2];
    const float* c_w = (const float*)d_in[3];
    const float* c_b = (const float*)d_in[4];
    const float* s_w = (const float*)d_in[5];
    const float* s_b = (const float*)d_in[6];
    const float* i_w = (const float*)d_in[7];
    const float* i_b = (const float*)d_in[8];
    const float* o_w = (const float*)d_in[9];
    const float* o_b = (const float*)d_in[10];
    float* out = (float*)d_out;
    char* ws = (char*)d_ws;

    const int B = 4, C = 512, N = 4096;
    const size_t NC = (size_t)N * C;
    const size_t W2 = (size_t)C * C;
    const size_t NN = (size_t)N * N;

    size_t off = 0;
    auto alloc = [&](size_t bytes) { size_t o = off; off += (bytes + 255) & ~(size_t)255; return o; };

    size_t o_meanC = alloc((size_t)B * C * 4);
    size_t o_rstdC = alloc((size_t)B * C * 4);
    size_t o_meanS = alloc((size_t)B * C * 4);
    size_t o_rstdS = alloc((size_t)B * C * 4);
    size_t o_cwT = alloc(W2 * 2);
    size_t o_swT = alloc(W2 * 2);
    size_t o_iwT = alloc(W2 * 2);
    size_t o_ow  = alloc(W2 * 2);
    size_t o_G   = alloc(W2 * 2);
    size_t o_W   = alloc(W2 * 2);
    size_t o_v   = alloc((size_t)C * 4);
    size_t o_wu  = alloc((size_t)C * 4);
    size_t o_u   = alloc((size_t)B * N * 4);
    size_t o_cnT = alloc(B * NC * 2);
    size_t o_snT = alloc(B * NC * 2);
    size_t o_sRT = alloc(B * NC * 2);
    size_t o_sgT = alloc(B * NC * 2);
    size_t o_sW  = alloc(B * NC * 2);
    size_t o_P   = alloc(2 * NN * 2);        // PAIR logits/P f16 (67MB)
    size_t o_pt  = alloc(8 * NC * 2);        // pair split-K4 partials f16

    if (ws_size < off) {
        (void)hipMemsetAsync(d_out, 0, (size_t)out_size * 4, stream);
        return;
    }

    float* meanC = (float*)(ws + o_meanC);
    float* rstdC = (float*)(ws + o_rstdC);
    float* meanS = (float*)(ws + o_meanS);
    float* rstdS = (float*)(ws + o_rstdS);
    u16* cwT = (u16*)(ws + o_cwT);
    u16* swT = (u16*)(ws + o_swT);
    u16* iwT = (u16*)(ws + o_iwT);
    u16* ow  = (u16*)(ws + o_ow);
    u16* Gf  = (u16*)(ws + o_G);
    u16* Wf  = (u16*)(ws + o_W);
    float* vb = (float*)(ws + o_v);
    float* wu = (float*)(ws + o_wu);
    float* ub = (float*)(ws + o_u);
    u16* cnT = (u16*)(ws + o_cnT);
    u16* snT = (u16*)(ws + o_snT);
    u16* sRT = (u16*)(ws + o_sRT);
    u16* sgT = (u16*)(ws + o_sgT);
    u16* sW  = (u16*)(ws + o_sW);
    u16* Pb  = (u16*)(ws + o_P);
    u16* partH = (u16*)(ws + o_pt);

    // 1) instance-norm stats
    stats_kernel<<<dim3(B * C, 2), 256, 0, stream>>>(c, s, meanC, rstdC, meanS, rstdS);
    // 2) fused packs
    packall<<<dim3(N / 32, C / 32, 8), dim3(32, 8), 0, stream>>>(
        c, s, meanC, rstdC, meanS, rstdS, cnT, snT, sRT);
    // 3) fused weight preps
    prep_kernel<<<dim3(16, 16, 4), dim3(32, 8), 0, stream>>>(
        c_w, s_w, i_w, o_w, cwT, swT, iwT, ow);
    bias_prep<<<dim3(4), 256, 0, stream>>>(o_w, i_b, o_b, s_w, c_b, vb, wu);
    // G[a,l] = c_w^T s_w  and  W[o,c] = o_w i_w  in one dispatch (M=N=512)
    gemm_bt<EPI_PLAIN_F16><<<dim3(4, 2, 2), 512, 0, stream>>>(
        cwT, swT, 512, 512, nullptr, nullptr, 0, nullptr, Gf, 512, 1,
        (long)(3 * W2), 0, (long)W2, 0, (long)W2);
    // 4) sgT[m,a] = sum_l snT[m,l]*G[a,l]  (M=4096, N=512)
    gemm_bt<EPI_PLAIN_F16><<<dim3(4, 16, B), 512, 0, stream>>>(
        snT, Gf, 512, 512, nullptr, nullptr, 0, nullptr, sgT, 512, 1,
        (long)NC, 0, 0, 0, (long)NC);
    // 5) sW[o,m] = sum_c W[o,c]*sRT[m,c]  (M=512, N=4096)
    gemm_bt<EPI_PLAIN_F16><<<dim3(32, 2, B), 512, 0, stream>>>(
        Wf, sRT, 512, 512, nullptr, nullptr, 0, nullptr, sW, 4096, 1,
        0, 0, (long)NC, 0, (long)NC);
    // 6) u[b,m] = sum_l snT[b,m,l]*wu[l]
    rowdot_kernel<<<dim3(B * N / 4), 256, 0, stream>>>(snT, wu, ub);
    // 7) attention in batch PAIRS
    for (int pb0 = 0; pb0 < B; pb0 += 2) {
        // logits: L[z,n,m] = cn.sg + u[m]  (M=N=4096, K=512; u fused as jb)
        gemm_bt<EPI_PLAIN_F16><<<dim3(32, 16, 2), 512, 0, stream>>>(
            cnT + (size_t)pb0 * NC, sgT + (size_t)pb0 * NC,
            512, 512, nullptr, ub + (size_t)pb0 * N, (long)N,
            nullptr, Pb, 4096, 1,
            (long)NC, 0, (long)NC, 0, (long)NN);
        // P = softmax_m(L) in place, 8192 rows
        softmax16<<<dim3(2 * N), 256, 0, stream>>>(Pb);
        // out_pre[o,n] = sum_m sW[o,m]*P[n,m]; split-K4, pair in one dispatch
        gemm_bt<EPI_PLAIN_F16><<<dim3(32, 2, 8), 512, 0, stream>>>(
            sW + (size_t)pb0 * NC, Pb, 1024, 4096, nullptr, nullptr, 0,
            nullptr, partH, 4096, 4,
            (long)NC, 1024L, (long)NN, 1024L, (long)NC);
        // out = sum partials + x + v
        reduce4resid<<<dim3((int)(NC / 2048), 2), 256, 0, stream>>>(
            partH, x + (size_t)pb0 * NC, vb, out + (size_t)pb0 * NC);
    }
}